// Round 2
// baseline (469.961 us; speedup 1.0000x reference)
//
#include <hip/hip_runtime.h>

#define NSLOT 32
#define BN_EPS 1e-5f

static inline int cdiv_h(int a, int b) { return (a + b - 1) / b; }

__device__ __forceinline__ float4 f4add(float4 a, float4 b) {
    return make_float4(a.x + b.x, a.y + b.y, a.z + b.z, a.w + b.w);
}

// bf16 round-to-nearest-even pack / unpack
__device__ __forceinline__ unsigned bf16rtn(float x) {
    unsigned u = __float_as_uint(x);
    return (u + 0x7FFFu + ((u >> 16) & 1u)) >> 16;
}
__device__ __forceinline__ unsigned bf16pack2(float lo, float hi) {
    return bf16rtn(lo) | (bf16rtn(hi) << 16);
}
__device__ __forceinline__ float bfLO(unsigned u) { return __uint_as_float(u << 16); }
__device__ __forceinline__ float bfHI(unsigned u) { return __uint_as_float(u & 0xFFFF0000u); }

// block-wide exclusive scan, 256 threads (4 waves)
__device__ __forceinline__ int blk_excl_scan256(int v, int t) {
    __shared__ int wsum[4];
    int l = t & 63, w = t >> 6;
    int incl = v;
#pragma unroll
    for (int off = 1; off < 64; off <<= 1) {
        int o = __shfl_up(incl, off, 64);
        if (l >= off) incl += o;
    }
    if (l == 63) wsum[w] = incl;
    __syncthreads();
    int wofs = 0;
#pragma unroll
    for (int i = 0; i < 4; i++) wofs += (i < w) ? wsum[i] : 0;
    __syncthreads();
    return wofs + incl - v;
}

// block-wide exclusive scan, 512 threads (8 waves)
__device__ __forceinline__ int blk_excl_scan512(int v, int t) {
    __shared__ int wsum8[8];
    int l = t & 63, w = t >> 6;
    int incl = v;
#pragma unroll
    for (int off = 1; off < 64; off <<= 1) {
        int o = __shfl_up(incl, off, 64);
        if (l >= off) incl += o;
    }
    if (l == 63) wsum8[w] = incl;
    __syncthreads();
    int wofs = 0;
#pragma unroll
    for (int i = 0; i < 8; i++) wofs += (i < w) ? wsum8[i] : 0;
    __syncthreads();
    return wofs + incl - v;
}

// per-block BN coef compute from 32-slot partials (ch in [0,32))
__device__ __forceinline__ void bn_coef(const float* __restrict__ sSum, const float* __restrict__ sSq,
                                        const float* __restrict__ bg, const float* __restrict__ bb,
                                        float invN, int ch, float* aOut, float* cOut) {
    float S = 0.f, Q = 0.f;
#pragma unroll
    for (int s = 0; s < NSLOT; s++) { S += sSum[s * 32 + ch]; Q += sSq[s * 32 + ch]; }
    float m = S * invN;
    float var = Q * invN - m * m;
    if (var < 0.f) var = 0.f;
    float iv = rsqrtf(var + BN_EPS);
    float a = bg[ch] * iv;
    *aOut = a;
    *cOut = bb[ch] - m * a;
}

// ---------------- CSR build via global atomics (full occupancy, grid-stride) ----------------
// re[] triples as: deg histogram -> scatter cursor (init rs) -> final row-end after k_scat.

__global__ __launch_bounds__(256) void k_zero(float* __restrict__ sSum, float* __restrict__ sSq,
                                              int* __restrict__ re, int N) {
    int i = blockIdx.x * 256 + threadIdx.x;
    int st = gridDim.x * 256;
    for (int k = i; k < N; k += st) re[k] = 0;
    if (i < 4 * NSLOT * 32) { sSum[i] = 0.f; sSq[i] = 0.f; }
}

__global__ __launch_bounds__(256) void k_deg(const int* __restrict__ dst, int* __restrict__ re, int E) {
    int i = blockIdx.x * 256 + threadIdx.x, st = gridDim.x * 256;
    for (; i < E; i += st) atomicAdd(&re[dst[i]], 1);   // no return use -> fire-and-forget
}

__global__ __launch_bounds__(256) void k_scanP(const int* __restrict__ re, int* __restrict__ rs,
                                               int* __restrict__ partial, int N) {
    int b = blockIdx.x, t = threadIdx.x, i = b * 256 + t;
    int v = (i < N) ? re[i] : 0;
    int ex = blk_excl_scan256(v, t);
    if (i < N) rs[i] = ex;
    if (t == 255) partial[b] = ex + v;
}

__global__ __launch_bounds__(512) void k_scanS(const int* __restrict__ partial, int* __restrict__ basep, int nb) {
    int t = threadIdx.x;
    int v = (t < nb) ? partial[t] : 0;
    int ex = blk_excl_scan512(v, t);
    if (t < nb) basep[t] = ex;
}

__global__ __launch_bounds__(256) void k_scan3(int* __restrict__ rs, int* __restrict__ re,
                                               const int* __restrict__ basep,
                                               const int* __restrict__ gid, int* __restrict__ gstart,
                                               int N, int G) {
    int b = blockIdx.x, t = threadIdx.x, i = b * 256 + t;
    if (i < N) {
        int g = gid[i];
        int gp = (i == 0) ? -1 : gid[i - 1];
        for (int x = gp + 1; x <= g; ++x) gstart[x] = i;
        if (i == N - 1) { for (int x = g + 1; x <= G; ++x) gstart[x] = N; }
        int r = rs[i] + basep[b];
        rs[i] = r;
        re[i] = r;          // cursor start; k_scat advances it to the row end
    }
}

__global__ __launch_bounds__(256) void k_scat(const int* __restrict__ src, const int* __restrict__ dst,
                                              int* __restrict__ re, int* __restrict__ col, int E) {
    int i = blockIdx.x * 256 + threadIdx.x, st = gridDim.x * 256;
    for (; i < E; i += st) {
        int d = dst[i], s = src[i];
        int pos = atomicAdd(&re[d], 1);
        col[pos] = s;
    }
}

// ---------------- per-node transform: p = (relu(a*y+c)) @ W -> bf16 (or h @ W for layer 0) --------
// AFF=1: input y is bf16 (uint4 x4 per node); folds previous layer's BN finalize.

template <int AFF>
__global__ __launch_bounds__(256) void k_transform(const void* __restrict__ xin, const float* __restrict__ W,
                                                   const float* __restrict__ sSum, const float* __restrict__ sSq,
                                                   const float* __restrict__ bg, const float* __restrict__ bb,
                                                   uint4* __restrict__ pb, int n, float invN) {
    __shared__ float sW[32][32];
    __shared__ float sA[32], sC[32];
    int t = threadIdx.x;
    for (int i = t; i < 1024; i += 256) sW[i >> 5][i & 31] = W[i];
    if (AFF && t < 32) bn_coef(sSum, sSq, bg, bb, invN, t, &sA[t], &sC[t]);
    __syncthreads();
    int node = blockIdx.x * 256 + t;
    if (node >= n) return;
    float x[32];
    if (AFF) {
        const uint4* y4 = (const uint4*)xin + (size_t)node * 4;
#pragma unroll
        for (int q = 0; q < 4; q++) {
            uint4 u = y4[q];
            x[8*q+0] = bfLO(u.x); x[8*q+1] = bfHI(u.x);
            x[8*q+2] = bfLO(u.y); x[8*q+3] = bfHI(u.y);
            x[8*q+4] = bfLO(u.z); x[8*q+5] = bfHI(u.z);
            x[8*q+6] = bfLO(u.w); x[8*q+7] = bfHI(u.w);
        }
#pragma unroll
        for (int k = 0; k < 32; k++) {
            float v = sA[k] * x[k] + sC[k];
            x[k] = v > 0.f ? v : 0.f;
        }
    } else {
        const float4* s4 = (const float4*)xin + (size_t)node * 8;
#pragma unroll
        for (int q = 0; q < 8; q++) {
            float4 v = s4[q];
            x[4*q] = v.x; x[4*q+1] = v.y; x[4*q+2] = v.z; x[4*q+3] = v.w;
        }
    }
    float acc[32];
#pragma unroll
    for (int f = 0; f < 32; f++) acc[f] = 0.f;
#pragma unroll
    for (int k = 0; k < 32; k++) {
        float xv = x[k];
#pragma unroll
        for (int f = 0; f < 32; f++) acc[f] += xv * sW[k][f];
    }
    uint4* d4 = pb + (size_t)node * 4;
#pragma unroll
    for (int q = 0; q < 4; q++) {
        uint4 o;
        o.x = bf16pack2(acc[8*q+0], acc[8*q+1]);
        o.y = bf16pack2(acc[8*q+2], acc[8*q+3]);
        o.z = bf16pack2(acc[8*q+4], acc[8*q+5]);
        o.w = bf16pack2(acc[8*q+6], acc[8*q+7]);
        d4[q] = o;
    }
}

// layer 3: p3[v] = relu(a*y2+c) . w3   (bf16 y2 input, fp32 out; folds its BN coefs)
__global__ __launch_bounds__(256) void k_transform3(const uint4* __restrict__ y2, const float* __restrict__ w3,
                                                    const float* __restrict__ sSum, const float* __restrict__ sSq,
                                                    const float* __restrict__ bg, const float* __restrict__ bb,
                                                    float* __restrict__ p3, int n, float invN) {
    __shared__ float sw[32], sA[32], sC[32];
    int t = threadIdx.x;
    if (t < 32) { sw[t] = w3[t]; bn_coef(sSum, sSq, bg, bb, invN, t, &sA[t], &sC[t]); }
    __syncthreads();
    int i = blockIdx.x * 256 + t;
    if (i >= n) return;
    const uint4* x4 = y2 + (size_t)i * 4;
    float acc = 0.f;
#pragma unroll
    for (int q = 0; q < 4; q++) {
        uint4 u = x4[q];
        float vv[8] = { bfLO(u.x), bfHI(u.x), bfLO(u.y), bfHI(u.y),
                        bfLO(u.z), bfHI(u.z), bfLO(u.w), bfHI(u.w) };
#pragma unroll
        for (int r = 0; r < 8; r++) {
            int k = q * 8 + r;
            float xv = sA[k] * vv[r] + sC[k];
            xv = xv > 0.f ? xv : 0.f;
            acc += xv * sw[k];
        }
    }
    p3[i] = acc;
}

// ---------------- aggregation: y[v] = mean_{u->v} p[u] + bias; fused BN stats; bf16 y out -------
// bf16 p: 4 lanes/node, 16B (8 bf16 ch)/lane, one node per 4-lane group, 4-deep unroll.
// Block's 64 nodes own a contiguous col window -> stage to LDS.
// __launch_bounds__(256,8): force VGPR<=64 -> 8 blocks/CU (32 waves) for gather latency hiding.

__global__ __launch_bounds__(256, 8) void k_aggregate(const uint4* __restrict__ pb, const int* __restrict__ rs,
                                                      const int* __restrict__ re, const int* __restrict__ col,
                                                      const float* __restrict__ bias,
                                                      uint4* __restrict__ yb, float* __restrict__ sSum,
                                                      float* __restrict__ sSq, int n) {
    __shared__ int scol[2048];
    __shared__ float sWS[4][32];
    __shared__ float sWQ[4][32];
    int t = threadIdx.x;
    int lane = t & 3;          // 16B chunk: channels lane*8 .. lane*8+7
    int grp = t >> 2;          // 0..63 : node within block
    int node0 = blockIdx.x * 64;
    int node = node0 + grp;
    int base0 = 0, len = 0;
    if (node0 < n) {
        int last = node0 + 63; if (last > n - 1) last = n - 1;
        base0 = rs[node0];
        len = re[last] - base0;
    }
    bool lds = (len > 0 && len <= 2048);    // block-uniform; mean 1024
    if (lds) { for (int i = t; i < len; i += 256) scol[i] = col[base0 + i]; }
    __syncthreads();

    float accA[8], accB[8];
#pragma unroll
    for (int q = 0; q < 8; q++) { accA[q] = 0.f; accB[q] = 0.f; }
    float vout[8];
#pragma unroll
    for (int q = 0; q < 8; q++) vout[q] = 0.f;
    if (node < n) {
        int s0 = rs[node], s1 = re[node];
#define GATH(vv, c) uint4 vv = pb[(size_t)(c) * 4 + lane]
#define ACC(dst, vv) \
        dst[0] += bfLO((vv).x); dst[1] += bfHI((vv).x); \
        dst[2] += bfLO((vv).y); dst[3] += bfHI((vv).y); \
        dst[4] += bfLO((vv).z); dst[5] += bfHI((vv).z); \
        dst[6] += bfLO((vv).w); dst[7] += bfHI((vv).w)
        if (lds) {
            int j = s0 - base0, j1 = s1 - base0;
            for (; j + 4 <= j1; j += 4) {
                int c0 = scol[j], c1 = scol[j + 1], c2 = scol[j + 2], c3 = scol[j + 3];
                GATH(g0, c0); GATH(g1, c1); GATH(g2, c2); GATH(g3, c3);
                ACC(accA, g0); ACC(accB, g1); ACC(accA, g2); ACC(accB, g3);
            }
            for (; j < j1; ++j) { GATH(g, scol[j]); ACC(accA, g); }
        } else {
            int j = s0;
            for (; j + 4 <= s1; j += 4) {
                int c0 = col[j], c1 = col[j + 1], c2 = col[j + 2], c3 = col[j + 3];
                GATH(g0, c0); GATH(g1, c1); GATH(g2, c2); GATH(g3, c3);
                ACC(accA, g0); ACC(accB, g1); ACC(accA, g2); ACC(accB, g3);
            }
            for (; j < s1; ++j) { GATH(g, col[j]); ACC(accA, g); }
        }
#undef GATH
#undef ACC
        int deg = s1 - s0;
        float inv = (deg > 0) ? 1.f / (float)deg : 1.f;
        const float4* b4 = (const float4*)bias;
        float4 b0 = b4[lane * 2], b1 = b4[lane * 2 + 1];
        vout[0] = (accA[0] + accB[0]) * inv + b0.x;
        vout[1] = (accA[1] + accB[1]) * inv + b0.y;
        vout[2] = (accA[2] + accB[2]) * inv + b0.z;
        vout[3] = (accA[3] + accB[3]) * inv + b0.w;
        vout[4] = (accA[4] + accB[4]) * inv + b1.x;
        vout[5] = (accA[5] + accB[5]) * inv + b1.y;
        vout[6] = (accA[6] + accB[6]) * inv + b1.z;
        vout[7] = (accA[7] + accB[7]) * inv + b1.w;
        uint4 o;
        o.x = bf16pack2(vout[0], vout[1]);
        o.y = bf16pack2(vout[2], vout[3]);
        o.z = bf16pack2(vout[4], vout[5]);
        o.w = bf16pack2(vout[6], vout[7]);
        yb[(size_t)node * 4 + lane] = o;
    }
    // BN stats (fp32, pre-rounding). Wave reduce across the 16 groups (lanes differing in bits 2..5).
    float sqv[8];
#pragma unroll
    for (int q = 0; q < 8; q++) sqv[q] = vout[q] * vout[q];
#pragma unroll
    for (int off = 4; off < 64; off <<= 1) {
#pragma unroll
        for (int q = 0; q < 8; q++) {
            vout[q] += __shfl_xor(vout[q], off, 64);
            sqv[q]  += __shfl_xor(sqv[q],  off, 64);
        }
    }
    int w = t >> 6, l = t & 63;
    if (l < 4) {
#pragma unroll
        for (int q = 0; q < 8; q++) { sWS[w][l * 8 + q] = vout[q]; sWQ[w][l * 8 + q] = sqv[q]; }
    }
    __syncthreads();
    if (t < 32) {
        float S = sWS[0][t] + sWS[1][t] + sWS[2][t] + sWS[3][t];
        float Q = sWQ[0][t] + sWQ[1][t] + sWQ[2][t] + sWQ[3][t];
        int slot = blockIdx.x & (NSLOT - 1);
        atomicAdd(&sSum[slot * 32 + t], S);
        atomicAdd(&sSq[slot * 32 + t], Q);
    }
}

__global__ __launch_bounds__(256) void k_aggregate3(const float* __restrict__ p3, const int* __restrict__ rs,
                                                    const int* __restrict__ re, const int* __restrict__ col,
                                                    const float* __restrict__ b1,
                                                    float* __restrict__ y3, float* __restrict__ sSum,
                                                    float* __restrict__ sSq, int n) {
    int t = threadIdx.x;
    int i = blockIdx.x * 256 + t;
    float lsum = 0.f, lsq = 0.f;
    if (i < n) {
        int s0 = rs[i], s1 = re[i];
        float a0 = 0.f, a1 = 0.f, a2 = 0.f, a3 = 0.f;
        int j = s0;
        for (; j + 4 <= s1; j += 4) {
            int c0 = col[j], c1 = col[j + 1], c2 = col[j + 2], c3 = col[j + 3];
            a0 += p3[c0]; a1 += p3[c1]; a2 += p3[c2]; a3 += p3[c3];
        }
        for (; j < s1; ++j) a0 += p3[col[j]];
        float acc = (a0 + a1) + (a2 + a3);
        float inv = (s1 > s0) ? 1.f / (float)(s1 - s0) : 1.f;
        float v = acc * inv + b1[0];
        y3[i] = v; lsum = v; lsq = v * v;
    }
#pragma unroll
    for (int off = 1; off < 64; off <<= 1) {
        lsum += __shfl_xor(lsum, off, 64);
        lsq  += __shfl_xor(lsq,  off, 64);
    }
    __shared__ float sWS3[4], sWQ3[4];
    if ((t & 63) == 0) { sWS3[t >> 6] = lsum; sWQ3[t >> 6] = lsq; }
    __syncthreads();
    if (t == 0) {
        float S = sWS3[0] + sWS3[1] + sWS3[2] + sWS3[3];
        float Q = sWQ3[0] + sWQ3[1] + sWQ3[2] + sWQ3[3];
        int slot = blockIdx.x & (NSLOT - 1);
        atomicAdd(&sSum[slot * 32], S);
        atomicAdd(&sSq[slot * 32], Q);
    }
}

// ---------------- per-graph mean pool + MLP (folds all 97 BN coefs; bf16 y inputs) --------------

__global__ __launch_bounds__(256) void k_pool_mlp(const float* __restrict__ h,
                                                  const unsigned* __restrict__ y0b,
                                                  const unsigned* __restrict__ y1b,
                                                  const unsigned* __restrict__ y2b,
                                                  const float* __restrict__ y3,
                                                  const float* __restrict__ sSum, const float* __restrict__ sSq,
                                                  const float* __restrict__ bg0, const float* __restrict__ bb0,
                                                  const float* __restrict__ bg1, const float* __restrict__ bb1,
                                                  const float* __restrict__ bg2, const float* __restrict__ bb2,
                                                  const float* __restrict__ bg3, const float* __restrict__ bb3,
                                                  const int* __restrict__ gstart,
                                                  const float* __restrict__ w0, const float* __restrict__ b0,
                                                  const float* __restrict__ w1, const float* __restrict__ b1,
                                                  const float* __restrict__ w2, const float* __restrict__ b2,
                                                  float* __restrict__ out, float invN) {
    __shared__ float pcA[128], pcC[128];
    int g = blockIdx.x;
    int t = threadIdx.x;
    if (t < 97) {
        int layer = (t == 96) ? 3 : (t >> 5);
        int ch = t & 31;
        const float* bg = (layer == 0) ? bg0 : (layer == 1) ? bg1 : (layer == 2) ? bg2 : bg3;
        const float* bb = (layer == 0) ? bb0 : (layer == 1) ? bb1 : (layer == 2) ? bb2 : bb3;
        bn_coef(sSum + layer * NSLOT * 32, sSq + layer * NSLOT * 32, bg, bb, invN, ch, &pcA[t], &pcC[t]);
    }
    __syncthreads();
    int s0 = gstart[g], s1 = gstart[g + 1];
    int lane = t & 31, slot = t >> 5;
    int arr = lane >> 3, sub = lane & 7;
    const unsigned* yb = (arr == 1) ? y0b : (arr == 2) ? y1b : y2b;
    float4 a4 = make_float4(1.f, 1.f, 1.f, 1.f);
    float4 c4 = make_float4(0.f, 0.f, 0.f, 0.f);
    bool aff = (arr > 0);
    if (aff) {
        a4 = ((const float4*)pcA)[(arr - 1) * 8 + sub];
        c4 = ((const float4*)pcC)[(arr - 1) * 8 + sub];
    }
    float4 acc = make_float4(0.f, 0.f, 0.f, 0.f);
    for (int n = s0 + slot; n < s1; n += 8) {
        float4 v;
        if (arr == 0) {
            v = ((const float4*)h)[(size_t)n * 8 + sub];
        } else {
            uint2 u = ((const uint2*)yb)[(size_t)n * 8 + sub];   // 4 bf16 ch
            v = make_float4(bfLO(u.x), bfHI(u.x), bfLO(u.y), bfHI(u.y));
        }
        if (aff) {
            float vx = fmaf(a4.x, v.x, c4.x); vx = vx > 0.f ? vx : 0.f;
            float vy = fmaf(a4.y, v.y, c4.y); vy = vy > 0.f ? vy : 0.f;
            float vz = fmaf(a4.z, v.z, c4.z); vz = vz > 0.f ? vz : 0.f;
            float vw = fmaf(a4.w, v.w, c4.w); vw = vw > 0.f ? vw : 0.f;
            v = make_float4(vx, vy, vz, vw);
        }
        acc = f4add(acc, v);
    }
    // y3 channel: all 256 threads accumulate, wave reduce, cross-wave combine in sY[4]
    float ys = 0.f;
    {
        float a = pcA[96], c = pcC[96];
        for (int n = s0 + t; n < s1; n += 256) {
            float v = fmaf(a, y3[n], c);
            ys += v > 0.f ? v : 0.f;
        }
    }
#pragma unroll
    for (int off = 1; off < 64; off <<= 1) ys += __shfl_xor(ys, off, 64);
    __shared__ float sP[8][128];
    __shared__ float sY[4];
    if ((t & 63) == 0) sY[t >> 6] = ys;
    ((float4*)&sP[slot][lane * 4])[0] = acc;
    __syncthreads();
    __shared__ float hg[129];
    __shared__ float hid1[128];
    __shared__ float hid2[64];
    float inv = (s1 > s0) ? 1.f / (float)(s1 - s0) : 1.f;
    if (t < 128) {
        float S = 0.f;
#pragma unroll
        for (int s = 0; s < 8; s++) S += sP[s][t];
        hg[t] = S * inv;
    } else if (t == 128) {
        float S = sY[0] + sY[1] + sY[2] + sY[3];
        hg[128] = S * inv;
    }
    __syncthreads();
    if (t < 128) {
        float a = b0[t];
        for (int i = 0; i < 129; i++) a += hg[i] * w0[i * 128 + t];
        hid1[t] = a > 0.f ? a : 0.f;
    }
    __syncthreads();
    if (t < 64) {
        float a = b1[t];
        for (int i = 0; i < 128; i++) a += hid1[i] * w1[i * 64 + t];
        hid2[t] = a > 0.f ? a : 0.f;
    }
    __syncthreads();
    if (t < 64) {
        float v = hid2[t] * w2[t];
        for (int off = 32; off > 0; off >>= 1) v += __shfl_down(v, off, 64);
        if (t == 0) out[g] = v + b2[0];
    }
}

// ---------------- launcher ----------------

extern "C" void kernel_launch(void* const* d_in, const int* in_sizes, int n_in,
                              void* d_out, int out_size, void* d_ws, size_t ws_size,
                              hipStream_t stream) {
    const float* h   = (const float*)d_in[0];
    const int* src   = (const int*)d_in[1];
    const int* dst   = (const int*)d_in[2];
    const int* gid   = (const int*)d_in[3];
    const float* convw[4], *convb[4], *bng[4], *bnb[4];
    for (int i = 0; i < 4; i++) {
        convw[i] = (const float*)d_in[4 + 4 * i];
        convb[i] = (const float*)d_in[5 + 4 * i];
        bng[i]   = (const float*)d_in[6 + 4 * i];
        bnb[i]   = (const float*)d_in[7 + 4 * i];
    }
    const float* mw0 = (const float*)d_in[20];
    const float* mb0 = (const float*)d_in[21];
    const float* mw1 = (const float*)d_in[22];
    const float* mb1 = (const float*)d_in[23];
    const float* mw2 = (const float*)d_in[24];
    const float* mb2 = (const float*)d_in[25];

    const int N = in_sizes[0] / 32;
    const int E = in_sizes[1];
    const int G = out_size;

    // workspace bump allocator (512B aligned)
    char* ws = (char*)d_ws;
    size_t off = 0;
    auto alloc = [&](size_t bytes) -> void* {
        void* p = ws + off;
        off += (bytes + 511) & ~(size_t)511;
        return p;
    };
    uint4* pb    = (uint4*)alloc((size_t)N * 64);              // p bf16: 64 B/node
    int* col     = (int*)alloc((size_t)E * 4);
    int* rs      = (int*)alloc((size_t)N * 4);
    int* re      = (int*)alloc((size_t)N * 4);
    int* partial = (int*)alloc((size_t)512 * 4);
    int* basep   = (int*)alloc((size_t)512 * 4);
    int* gstart  = (int*)alloc((size_t)(G + 1) * 4);
    uint4* y0b   = (uint4*)alloc((size_t)N * 64);              // bf16 y: 64 B/node
    uint4* y1b   = (uint4*)alloc((size_t)N * 64);
    uint4* y2b   = (uint4*)alloc((size_t)N * 64);
    float* y3    = (float*)alloc((size_t)N * 4);
    float* sSum  = (float*)alloc((size_t)4 * NSLOT * 32 * 4);
    float* sSq   = (float*)alloc((size_t)4 * NSLOT * 32 * 4);
    (void)ws_size; (void)n_in;

    const int NB_N = cdiv_h(N, 256);   // <= 512 for N <= 131072 (scanS bound)
    const int NB_AG = cdiv_h(N, 64);   // one node per 4-lane group
    const int NB_E = (cdiv_h(E, 256) < 2048) ? cdiv_h(E, 256) : 2048;
    const float invN = 1.f / (float)N;

    // CSR build: histogram -> scan -> atomic scatter (all full-occupancy grid-stride)
    k_zero<<<NB_N, 256, 0, stream>>>(sSum, sSq, re, N);
    k_deg<<<NB_E, 256, 0, stream>>>(dst, re, E);
    k_scanP<<<NB_N, 256, 0, stream>>>(re, rs, partial, N);
    k_scanS<<<1, 512, 0, stream>>>(partial, basep, NB_N);
    k_scan3<<<NB_N, 256, 0, stream>>>(rs, re, basep, gid, gstart, N, G);
    k_scat<<<NB_E, 256, 0, stream>>>(src, dst, re, col, E);

    // layer 0
    k_transform<0><<<NB_N, 256, 0, stream>>>(h, convw[0], nullptr, nullptr, nullptr, nullptr, pb, N, invN);
    k_aggregate<<<NB_AG, 256, 0, stream>>>(pb, rs, re, col, convb[0], y0b,
                                           sSum + 0 * NSLOT * 32, sSq + 0 * NSLOT * 32, N);
    // layer 1 (folds layer-0 BN finalize)
    k_transform<1><<<NB_N, 256, 0, stream>>>(y0b, convw[1], sSum + 0 * NSLOT * 32, sSq + 0 * NSLOT * 32,
                                             bng[0], bnb[0], pb, N, invN);
    k_aggregate<<<NB_AG, 256, 0, stream>>>(pb, rs, re, col, convb[1], y1b,
                                           sSum + 1 * NSLOT * 32, sSq + 1 * NSLOT * 32, N);
    // layer 2 (folds layer-1 BN finalize)
    k_transform<1><<<NB_N, 256, 0, stream>>>(y1b, convw[2], sSum + 1 * NSLOT * 32, sSq + 1 * NSLOT * 32,
                                             bng[1], bnb[1], pb, N, invN);
    k_aggregate<<<NB_AG, 256, 0, stream>>>(pb, rs, re, col, convb[2], y2b,
                                           sSum + 2 * NSLOT * 32, sSq + 2 * NSLOT * 32, N);
    // layer 3 (32 -> 1, pre-multiplied; folds layer-2 BN finalize)
    k_transform3<<<NB_N, 256, 0, stream>>>(y2b, convw[3], sSum + 2 * NSLOT * 32, sSq + 2 * NSLOT * 32,
                                           bng[2], bnb[2], (float*)pb, N, invN);
    k_aggregate3<<<NB_N, 256, 0, stream>>>((float*)pb, rs, re, col, convb[3], y3,
                                           sSum + 3 * NSLOT * 32, sSq + 3 * NSLOT * 32, N);

    // pooling + MLP (folds all BN coefs)
    k_pool_mlp<<<G, 256, 0, stream>>>(h, (const unsigned*)y0b, (const unsigned*)y1b, (const unsigned*)y2b,
                                      y3, sSum, sSq,
                                      bng[0], bnb[0], bng[1], bnb[1], bng[2], bnb[2], bng[3], bnb[3],
                                      gstart, mw0, mb0, mw1, mb1, mw2, mb2, (float*)d_out, invN);
}

// Round 3
// 306.737 us; speedup vs baseline: 1.5321x; 1.5321x over previous
//
#include <hip/hip_runtime.h>

#define NSLOT 32
#define BN_EPS 1e-5f
#define NSB 256             // scatter blocks (1 edge-slice each)
#define BKBITS 8
#define BKN 256             // nodes per bucket (= sort block size)
#define MAXBUCK 512         // LDS bound: nbuck = cdiv(N,256) <= 512 for N <= 131072

static inline int cdiv_h(int a, int b) { return (a + b - 1) / b; }

__device__ __forceinline__ float4 f4add(float4 a, float4 b) {
    return make_float4(a.x + b.x, a.y + b.y, a.z + b.z, a.w + b.w);
}

// bf16 round-to-nearest-even pack / unpack
__device__ __forceinline__ unsigned bf16rtn(float x) {
    unsigned u = __float_as_uint(x);
    return (u + 0x7FFFu + ((u >> 16) & 1u)) >> 16;
}
__device__ __forceinline__ unsigned bf16pack2(float lo, float hi) {
    return bf16rtn(lo) | (bf16rtn(hi) << 16);
}
__device__ __forceinline__ float bfLO(unsigned u) { return __uint_as_float(u << 16); }
__device__ __forceinline__ float bfHI(unsigned u) { return __uint_as_float(u & 0xFFFF0000u); }

// block-wide exclusive scan, 256 threads (4 waves)
__device__ __forceinline__ int blk_excl_scan256(int v, int t) {
    __shared__ int wsum[4];
    int l = t & 63, w = t >> 6;
    int incl = v;
#pragma unroll
    for (int off = 1; off < 64; off <<= 1) {
        int o = __shfl_up(incl, off, 64);
        if (l >= off) incl += o;
    }
    if (l == 63) wsum[w] = incl;
    __syncthreads();
    int wofs = 0;
#pragma unroll
    for (int i = 0; i < 4; i++) wofs += (i < w) ? wsum[i] : 0;
    __syncthreads();
    return wofs + incl - v;
}

// block-wide exclusive scan, 512 threads (8 waves)
__device__ __forceinline__ int blk_excl_scan512(int v, int t) {
    __shared__ int wsum8[8];
    int l = t & 63, w = t >> 6;
    int incl = v;
#pragma unroll
    for (int off = 1; off < 64; off <<= 1) {
        int o = __shfl_up(incl, off, 64);
        if (l >= off) incl += o;
    }
    if (l == 63) wsum8[w] = incl;
    __syncthreads();
    int wofs = 0;
#pragma unroll
    for (int i = 0; i < 8; i++) wofs += (i < w) ? wsum8[i] : 0;
    __syncthreads();
    return wofs + incl - v;
}

// per-block BN coef compute from 32-slot partials (ch in [0,32))
__device__ __forceinline__ void bn_coef(const float* __restrict__ sSum, const float* __restrict__ sSq,
                                        const float* __restrict__ bg, const float* __restrict__ bb,
                                        float invN, int ch, float* aOut, float* cOut) {
    float S = 0.f, Q = 0.f;
#pragma unroll
    for (int s = 0; s < NSLOT; s++) { S += sSum[s * 32 + ch]; Q += sSq[s * 32 + ch]; }
    float m = S * invN;
    float var = Q * invN - m * m;
    if (var < 0.f) var = 0.f;
    float iv = rsqrtf(var + BN_EPS);
    float a = bg[ch] * iv;
    *aOut = a;
    *cOut = bb[ch] - m * a;
}

// ---------------- grouping pass 1: per-block bucket histogram + stats zero-init ----------------

__global__ __launch_bounds__(256) void k_hist(const int* __restrict__ dst, int* __restrict__ histT,
                                              float* __restrict__ sSum, float* __restrict__ sSq,
                                              int E, int nbuck, int chunk) {
    __shared__ int bins[MAXBUCK];
    int k = blockIdx.x, t = threadIdx.x;
    if (k == 0) {    // zero BN stat slots (replaces memsets)
        for (int i = t; i < 4 * NSLOT * 32; i += 256) { sSum[i] = 0.f; sSq[i] = 0.f; }
    }
    for (int b = t; b < nbuck; b += 256) bins[b] = 0;
    __syncthreads();
    int lo = k * chunk, hi = lo + chunk; if (hi > E) hi = E;
    for (int i = lo + t; i < hi; i += 256) atomicAdd(&bins[dst[i] >> BKBITS], 1);
    __syncthreads();
    for (int b = t; b < nbuck; b += 256) histT[k * nbuck + b] = bins[b];
}

// ---------------- grouping pass 1b: per-bucket scan over cells (+ folded gstart) ----------------

__global__ __launch_bounds__(256) void k_scanA(const int* __restrict__ histT, int* __restrict__ prefixB,
                                               int* __restrict__ totalP, int* __restrict__ totalU,
                                               const int* __restrict__ gid, int* __restrict__ gstart,
                                               int nbuck, int N, int G) {
    int b = blockIdx.x, k = threadIdx.x;
    int i = b * 256 + k;
    if (i < N) {
        int g = gid[i];
        int gp = (i == 0) ? -1 : gid[i - 1];
        for (int x = gp + 1; x <= g; ++x) gstart[x] = i;
        if (i == N - 1) { for (int x = g + 1; x <= G; ++x) gstart[x] = N; }
    }
    int c = histT[k * nbuck + b];
    int pad = (c + 15) & ~15;
    int ep = blk_excl_scan256(pad, k);
    prefixB[b * NSB + k] = ep;
    int ec = blk_excl_scan256(c, k);
    if (k == NSB - 1) { totalP[b] = ep + pad; totalU[b] = ec + c; }
}

__global__ __launch_bounds__(512) void k_scanB(const int* __restrict__ totalP, const int* __restrict__ totalU,
                                               int* __restrict__ baseP, int* __restrict__ baseU, int nbuck) {
    int t = threadIdx.x;
    int vp = (t < nbuck) ? totalP[t] : 0;
    int vu = (t < nbuck) ? totalU[t] : 0;
    int ep = blk_excl_scan512(vp, t);
    int eu = blk_excl_scan512(vu, t);
    if (t < nbuck) { baseP[t] = ep; baseU[t] = eu; }
}

// ---------------- grouping pass 2: deterministic scatter (LDS cursors, no global atomics) --------
// packed entry: (dst&255)<<24 | src   (requires N < 2^24)

__global__ __launch_bounds__(256) void k_scatter2(const int* __restrict__ src, const int* __restrict__ dst,
                                                  const int* __restrict__ baseP, const int* __restrict__ prefixB,
                                                  unsigned* __restrict__ ebuf, int E, int nbuck, int chunk) {
    __shared__ int cur[MAXBUCK];
    int k = blockIdx.x, t = threadIdx.x;
    for (int b = t; b < nbuck; b += 256) cur[b] = baseP[b] + prefixB[b * NSB + k];
    __syncthreads();
    int lo = k * chunk, hi = lo + chunk; if (hi > E) hi = E;
    for (int i = lo + t; i < hi; i += 256) {
        int d = dst[i], s = src[i];
        int b = d >> BKBITS;
        int pos = atomicAdd(&cur[b], 1);
        ebuf[pos] = ((unsigned)(d & (BKN - 1)) << 24) | (unsigned)s;
    }
}

// ---------------- grouping pass 3: per-bucket counting sort -> node-grouped compact col + rs/re --

__global__ __launch_bounds__(256) void k_sortb(const unsigned* __restrict__ ebuf, const int* __restrict__ histT,
                                               const int* __restrict__ baseP, const int* __restrict__ prefixB,
                                               const int* __restrict__ baseU,
                                               int* __restrict__ col, int* __restrict__ rs, int* __restrict__ re,
                                               int nbuck, int N) {
    __shared__ int binCnt[BKN], binStart[BKN], cursor[BKN];
    __shared__ int cellBase[NSB], cellCnt[NSB];
    int b = blockIdx.x, t = threadIdx.x;
    cellBase[t] = baseP[b] + prefixB[b * NSB + t];
    cellCnt[t]  = histT[t * nbuck + b];
    binCnt[t] = 0; cursor[t] = 0;
    __syncthreads();
    {
        int cb = cellBase[t], cc = cellCnt[t];
        for (int j = 0; j < cc; j++) atomicAdd(&binCnt[ebuf[cb + j] >> 24], 1);
    }
    __syncthreads();
    int bs = blk_excl_scan256(binCnt[t], t);
    binStart[t] = bs;
    __syncthreads();
    int colBase = baseU[b];
    {
        int cb = cellBase[t], cc = cellCnt[t];
        for (int j = 0; j < cc; j++) {
            unsigned e = ebuf[cb + j];
            int l = e >> 24;
            int pos = binStart[l] + atomicAdd(&cursor[l], 1);
            col[colBase + pos] = (int)(e & 0xFFFFFFu);
        }
    }
    int node = b * BKN + t;
    if (node < N) {
        rs[node] = colBase + binStart[t];
        re[node] = colBase + binStart[t] + binCnt[t];
    }
}

// ---------------- per-node transform: p = (relu(a*y+c)) @ W -> bf16 (or h @ W for layer 0) --------
// AFF=1: input y is bf16 (uint4 x4 per node); folds previous layer's BN finalize.

template <int AFF>
__global__ __launch_bounds__(256) void k_transform(const void* __restrict__ xin, const float* __restrict__ W,
                                                   const float* __restrict__ sSum, const float* __restrict__ sSq,
                                                   const float* __restrict__ bg, const float* __restrict__ bb,
                                                   uint4* __restrict__ pb, int n, float invN) {
    __shared__ float sW[32][32];
    __shared__ float sA[32], sC[32];
    int t = threadIdx.x;
    for (int i = t; i < 1024; i += 256) sW[i >> 5][i & 31] = W[i];
    if (AFF && t < 32) bn_coef(sSum, sSq, bg, bb, invN, t, &sA[t], &sC[t]);
    __syncthreads();
    int node = blockIdx.x * 256 + t;
    if (node >= n) return;
    float x[32];
    if (AFF) {
        const uint4* y4 = (const uint4*)xin + (size_t)node * 4;
#pragma unroll
        for (int q = 0; q < 4; q++) {
            uint4 u = y4[q];
            x[8*q+0] = bfLO(u.x); x[8*q+1] = bfHI(u.x);
            x[8*q+2] = bfLO(u.y); x[8*q+3] = bfHI(u.y);
            x[8*q+4] = bfLO(u.z); x[8*q+5] = bfHI(u.z);
            x[8*q+6] = bfLO(u.w); x[8*q+7] = bfHI(u.w);
        }
#pragma unroll
        for (int k = 0; k < 32; k++) {
            float v = sA[k] * x[k] + sC[k];
            x[k] = v > 0.f ? v : 0.f;
        }
    } else {
        const float4* s4 = (const float4*)xin + (size_t)node * 8;
#pragma unroll
        for (int q = 0; q < 8; q++) {
            float4 v = s4[q];
            x[4*q] = v.x; x[4*q+1] = v.y; x[4*q+2] = v.z; x[4*q+3] = v.w;
        }
    }
    float acc[32];
#pragma unroll
    for (int f = 0; f < 32; f++) acc[f] = 0.f;
#pragma unroll
    for (int k = 0; k < 32; k++) {
        float xv = x[k];
#pragma unroll
        for (int f = 0; f < 32; f++) acc[f] += xv * sW[k][f];
    }
    uint4* d4 = pb + (size_t)node * 4;
#pragma unroll
    for (int q = 0; q < 4; q++) {
        uint4 o;
        o.x = bf16pack2(acc[8*q+0], acc[8*q+1]);
        o.y = bf16pack2(acc[8*q+2], acc[8*q+3]);
        o.z = bf16pack2(acc[8*q+4], acc[8*q+5]);
        o.w = bf16pack2(acc[8*q+6], acc[8*q+7]);
        d4[q] = o;
    }
}

// layer 3: p3[v] = relu(a*y2+c) . w3   (bf16 y2 input, fp32 out; folds its BN coefs)
__global__ __launch_bounds__(256) void k_transform3(const uint4* __restrict__ y2, const float* __restrict__ w3,
                                                    const float* __restrict__ sSum, const float* __restrict__ sSq,
                                                    const float* __restrict__ bg, const float* __restrict__ bb,
                                                    float* __restrict__ p3, int n, float invN) {
    __shared__ float sw[32], sA[32], sC[32];
    int t = threadIdx.x;
    if (t < 32) { sw[t] = w3[t]; bn_coef(sSum, sSq, bg, bb, invN, t, &sA[t], &sC[t]); }
    __syncthreads();
    int i = blockIdx.x * 256 + t;
    if (i >= n) return;
    const uint4* x4 = y2 + (size_t)i * 4;
    float acc = 0.f;
#pragma unroll
    for (int q = 0; q < 4; q++) {
        uint4 u = x4[q];
        float vv[8] = { bfLO(u.x), bfHI(u.x), bfLO(u.y), bfHI(u.y),
                        bfLO(u.z), bfHI(u.z), bfLO(u.w), bfHI(u.w) };
#pragma unroll
        for (int r = 0; r < 8; r++) {
            int k = q * 8 + r;
            float xv = sA[k] * vv[r] + sC[k];
            xv = xv > 0.f ? xv : 0.f;
            acc += xv * sw[k];
        }
    }
    p3[i] = acc;
}

// ---------------- aggregation: y[v] = mean_{u->v} p[u] + bias; fused BN stats; bf16 y out -------
// bf16 p: 4 lanes/node, 16B (8 bf16 ch)/lane, one node per 4-lane group.
// Software-pipelined gather: quad j+4 is issued BEFORE quad j's accumulate, so 8 loads stay
// in flight during the VALU block (compiler alone does not rotate loads across iterations).
// launch_bounds(256,6): 24 waves/CU under the ~80 VGPR this needs (double-buffer = +16 VGPR).

__global__ __launch_bounds__(256, 6) void k_aggregate(const uint4* __restrict__ pb, const int* __restrict__ rs,
                                                      const int* __restrict__ re, const int* __restrict__ col,
                                                      const float* __restrict__ bias,
                                                      uint4* __restrict__ yb, float* __restrict__ sSum,
                                                      float* __restrict__ sSq, int n) {
    __shared__ int scol[2048];
    __shared__ float sWS[4][32];
    __shared__ float sWQ[4][32];
    int t = threadIdx.x;
    int lane = t & 3;          // 16B chunk: channels lane*8 .. lane*8+7
    int grp = t >> 2;          // 0..63 : node within block
    int node0 = blockIdx.x * 64;
    int node = node0 + grp;
    int base0 = 0, len = 0;
    if (node0 < n) {
        int last = node0 + 63; if (last > n - 1) last = n - 1;
        base0 = rs[node0];
        len = re[last] - base0;
    }
    bool lds = (len > 0 && len <= 2048);    // block-uniform; mean 1024
    if (lds) { for (int i = t; i < len; i += 256) scol[i] = col[base0 + i]; }
    __syncthreads();

    float accA[8], accB[8];
#pragma unroll
    for (int q = 0; q < 8; q++) { accA[q] = 0.f; accB[q] = 0.f; }
    float vout[8];
#pragma unroll
    for (int q = 0; q < 8; q++) vout[q] = 0.f;
    if (node < n) {
        int s0 = rs[node], s1 = re[node];
#define GATH2(vv, c) vv = pb[(size_t)(c) * 4 + lane]
#define ACC(dst, vv) \
        dst[0] += bfLO((vv).x); dst[1] += bfHI((vv).x); \
        dst[2] += bfLO((vv).y); dst[3] += bfHI((vv).y); \
        dst[4] += bfLO((vv).z); dst[5] += bfHI((vv).z); \
        dst[6] += bfLO((vv).w); dst[7] += bfHI((vv).w)
        if (lds) {
            int j = s0 - base0, j1 = s1 - base0;
            if (j + 4 <= j1) {
                uint4 g0, g1, g2, g3;
                GATH2(g0, scol[j]); GATH2(g1, scol[j + 1]); GATH2(g2, scol[j + 2]); GATH2(g3, scol[j + 3]);
                j += 4;
                for (; j + 4 <= j1; j += 4) {
                    uint4 h0, h1, h2, h3;
                    GATH2(h0, scol[j]); GATH2(h1, scol[j + 1]); GATH2(h2, scol[j + 2]); GATH2(h3, scol[j + 3]);
                    ACC(accA, g0); ACC(accB, g1); ACC(accA, g2); ACC(accB, g3);
                    g0 = h0; g1 = h1; g2 = h2; g3 = h3;
                }
                ACC(accA, g0); ACC(accB, g1); ACC(accA, g2); ACC(accB, g3);
            }
            for (; j < j1; ++j) { uint4 g; GATH2(g, scol[j]); ACC(accA, g); }
        } else {
            int j = s0;
            if (j + 4 <= s1) {
                uint4 g0, g1, g2, g3;
                GATH2(g0, col[j]); GATH2(g1, col[j + 1]); GATH2(g2, col[j + 2]); GATH2(g3, col[j + 3]);
                j += 4;
                for (; j + 4 <= s1; j += 4) {
                    uint4 h0, h1, h2, h3;
                    GATH2(h0, col[j]); GATH2(h1, col[j + 1]); GATH2(h2, col[j + 2]); GATH2(h3, col[j + 3]);
                    ACC(accA, g0); ACC(accB, g1); ACC(accA, g2); ACC(accB, g3);
                    g0 = h0; g1 = h1; g2 = h2; g3 = h3;
                }
                ACC(accA, g0); ACC(accB, g1); ACC(accA, g2); ACC(accB, g3);
            }
            for (; j < s1; ++j) { uint4 g; GATH2(g, col[j]); ACC(accA, g); }
        }
#undef GATH2
#undef ACC
        int deg = s1 - s0;
        float inv = (deg > 0) ? 1.f / (float)deg : 1.f;
        const float4* b4 = (const float4*)bias;
        float4 b0 = b4[lane * 2], b1 = b4[lane * 2 + 1];
        vout[0] = (accA[0] + accB[0]) * inv + b0.x;
        vout[1] = (accA[1] + accB[1]) * inv + b0.y;
        vout[2] = (accA[2] + accB[2]) * inv + b0.z;
        vout[3] = (accA[3] + accB[3]) * inv + b0.w;
        vout[4] = (accA[4] + accB[4]) * inv + b1.x;
        vout[5] = (accA[5] + accB[5]) * inv + b1.y;
        vout[6] = (accA[6] + accB[6]) * inv + b1.z;
        vout[7] = (accA[7] + accB[7]) * inv + b1.w;
        uint4 o;
        o.x = bf16pack2(vout[0], vout[1]);
        o.y = bf16pack2(vout[2], vout[3]);
        o.z = bf16pack2(vout[4], vout[5]);
        o.w = bf16pack2(vout[6], vout[7]);
        yb[(size_t)node * 4 + lane] = o;
    }
    // BN stats (fp32, pre-rounding). Wave reduce across the 16 groups (lanes differing in bits 2..5).
    float sqv[8];
#pragma unroll
    for (int q = 0; q < 8; q++) sqv[q] = vout[q] * vout[q];
#pragma unroll
    for (int off = 4; off < 64; off <<= 1) {
#pragma unroll
        for (int q = 0; q < 8; q++) {
            vout[q] += __shfl_xor(vout[q], off, 64);
            sqv[q]  += __shfl_xor(sqv[q],  off, 64);
        }
    }
    int w = t >> 6, l = t & 63;
    if (l < 4) {
#pragma unroll
        for (int q = 0; q < 8; q++) { sWS[w][l * 8 + q] = vout[q]; sWQ[w][l * 8 + q] = sqv[q]; }
    }
    __syncthreads();
    if (t < 32) {
        float S = sWS[0][t] + sWS[1][t] + sWS[2][t] + sWS[3][t];
        float Q = sWQ[0][t] + sWQ[1][t] + sWQ[2][t] + sWQ[3][t];
        int slot = blockIdx.x & (NSLOT - 1);
        atomicAdd(&sSum[slot * 32 + t], S);
        atomicAdd(&sSq[slot * 32 + t], Q);
    }
}

__global__ __launch_bounds__(256) void k_aggregate3(const float* __restrict__ p3, const int* __restrict__ rs,
                                                    const int* __restrict__ re, const int* __restrict__ col,
                                                    const float* __restrict__ b1,
                                                    float* __restrict__ y3, float* __restrict__ sSum,
                                                    float* __restrict__ sSq, int n) {
    int t = threadIdx.x;
    int i = blockIdx.x * 256 + t;
    float lsum = 0.f, lsq = 0.f;
    if (i < n) {
        int s0 = rs[i], s1 = re[i];
        float a0 = 0.f, a1 = 0.f, a2 = 0.f, a3 = 0.f;
        int j = s0;
        if (j + 4 <= s1) {
            float g0 = p3[col[j]], g1 = p3[col[j + 1]], g2 = p3[col[j + 2]], g3 = p3[col[j + 3]];
            j += 4;
            for (; j + 4 <= s1; j += 4) {
                float h0 = p3[col[j]], h1 = p3[col[j + 1]], h2 = p3[col[j + 2]], h3 = p3[col[j + 3]];
                a0 += g0; a1 += g1; a2 += g2; a3 += g3;
                g0 = h0; g1 = h1; g2 = h2; g3 = h3;
            }
            a0 += g0; a1 += g1; a2 += g2; a3 += g3;
        }
        for (; j < s1; ++j) a0 += p3[col[j]];
        float acc = (a0 + a1) + (a2 + a3);
        float inv = (s1 > s0) ? 1.f / (float)(s1 - s0) : 1.f;
        float v = acc * inv + b1[0];
        y3[i] = v; lsum = v; lsq = v * v;
    }
#pragma unroll
    for (int off = 1; off < 64; off <<= 1) {
        lsum += __shfl_xor(lsum, off, 64);
        lsq  += __shfl_xor(lsq,  off, 64);
    }
    __shared__ float sWS3[4], sWQ3[4];
    if ((t & 63) == 0) { sWS3[t >> 6] = lsum; sWQ3[t >> 6] = lsq; }
    __syncthreads();
    if (t == 0) {
        float S = sWS3[0] + sWS3[1] + sWS3[2] + sWS3[3];
        float Q = sWQ3[0] + sWQ3[1] + sWQ3[2] + sWQ3[3];
        int slot = blockIdx.x & (NSLOT - 1);
        atomicAdd(&sSum[slot * 32], S);
        atomicAdd(&sSq[slot * 32], Q);
    }
}

// ---------------- per-graph mean pool + MLP (folds all 97 BN coefs; bf16 y inputs) --------------

__global__ __launch_bounds__(256) void k_pool_mlp(const float* __restrict__ h,
                                                  const unsigned* __restrict__ y0b,
                                                  const unsigned* __restrict__ y1b,
                                                  const unsigned* __restrict__ y2b,
                                                  const float* __restrict__ y3,
                                                  const float* __restrict__ sSum, const float* __restrict__ sSq,
                                                  const float* __restrict__ bg0, const float* __restrict__ bb0,
                                                  const float* __restrict__ bg1, const float* __restrict__ bb1,
                                                  const float* __restrict__ bg2, const float* __restrict__ bb2,
                                                  const float* __restrict__ bg3, const float* __restrict__ bb3,
                                                  const int* __restrict__ gstart,
                                                  const float* __restrict__ w0, const float* __restrict__ b0,
                                                  const float* __restrict__ w1, const float* __restrict__ b1,
                                                  const float* __restrict__ w2, const float* __restrict__ b2,
                                                  float* __restrict__ out, float invN) {
    __shared__ float pcA[128], pcC[128];
    int g = blockIdx.x;
    int t = threadIdx.x;
    if (t < 97) {
        int layer = (t == 96) ? 3 : (t >> 5);
        int ch = t & 31;
        const float* bg = (layer == 0) ? bg0 : (layer == 1) ? bg1 : (layer == 2) ? bg2 : bg3;
        const float* bb = (layer == 0) ? bb0 : (layer == 1) ? bb1 : (layer == 2) ? bb2 : bb3;
        bn_coef(sSum + layer * NSLOT * 32, sSq + layer * NSLOT * 32, bg, bb, invN, ch, &pcA[t], &pcC[t]);
    }
    __syncthreads();
    int s0 = gstart[g], s1 = gstart[g + 1];
    int lane = t & 31, slot = t >> 5;
    int arr = lane >> 3, sub = lane & 7;
    const unsigned* yb = (arr == 1) ? y0b : (arr == 2) ? y1b : y2b;
    float4 a4 = make_float4(1.f, 1.f, 1.f, 1.f);
    float4 c4 = make_float4(0.f, 0.f, 0.f, 0.f);
    bool aff = (arr > 0);
    if (aff) {
        a4 = ((const float4*)pcA)[(arr - 1) * 8 + sub];
        c4 = ((const float4*)pcC)[(arr - 1) * 8 + sub];
    }
    float4 acc = make_float4(0.f, 0.f, 0.f, 0.f);
    for (int n = s0 + slot; n < s1; n += 8) {
        float4 v;
        if (arr == 0) {
            v = ((const float4*)h)[(size_t)n * 8 + sub];
        } else {
            uint2 u = ((const uint2*)yb)[(size_t)n * 8 + sub];   // 4 bf16 ch
            v = make_float4(bfLO(u.x), bfHI(u.x), bfLO(u.y), bfHI(u.y));
        }
        if (aff) {
            float vx = fmaf(a4.x, v.x, c4.x); vx = vx > 0.f ? vx : 0.f;
            float vy = fmaf(a4.y, v.y, c4.y); vy = vy > 0.f ? vy : 0.f;
            float vz = fmaf(a4.z, v.z, c4.z); vz = vz > 0.f ? vz : 0.f;
            float vw = fmaf(a4.w, v.w, c4.w); vw = vw > 0.f ? vw : 0.f;
            v = make_float4(vx, vy, vz, vw);
        }
        acc = f4add(acc, v);
    }
    // y3 channel: all 256 threads accumulate, wave reduce, cross-wave combine in sY[4]
    float ys = 0.f;
    {
        float a = pcA[96], c = pcC[96];
        for (int n = s0 + t; n < s1; n += 256) {
            float v = fmaf(a, y3[n], c);
            ys += v > 0.f ? v : 0.f;
        }
    }
#pragma unroll
    for (int off = 1; off < 64; off <<= 1) ys += __shfl_xor(ys, off, 64);
    __shared__ float sP[8][128];
    __shared__ float sY[4];
    if ((t & 63) == 0) sY[t >> 6] = ys;
    ((float4*)&sP[slot][lane * 4])[0] = acc;
    __syncthreads();
    __shared__ float hg[129];
    __shared__ float hid1[128];
    __shared__ float hid2[64];
    float inv = (s1 > s0) ? 1.f / (float)(s1 - s0) : 1.f;
    if (t < 128) {
        float S = 0.f;
#pragma unroll
        for (int s = 0; s < 8; s++) S += sP[s][t];
        hg[t] = S * inv;
    } else if (t == 128) {
        float S = sY[0] + sY[1] + sY[2] + sY[3];
        hg[128] = S * inv;
    }
    __syncthreads();
    if (t < 128) {
        float a = b0[t];
        for (int i = 0; i < 129; i++) a += hg[i] * w0[i * 128 + t];
        hid1[t] = a > 0.f ? a : 0.f;
    }
    __syncthreads();
    if (t < 64) {
        float a = b1[t];
        for (int i = 0; i < 128; i++) a += hid1[i] * w1[i * 64 + t];
        hid2[t] = a > 0.f ? a : 0.f;
    }
    __syncthreads();
    if (t < 64) {
        float v = hid2[t] * w2[t];
        for (int off = 32; off > 0; off >>= 1) v += __shfl_down(v, off, 64);
        if (t == 0) out[g] = v + b2[0];
    }
}

// ---------------- launcher ----------------

extern "C" void kernel_launch(void* const* d_in, const int* in_sizes, int n_in,
                              void* d_out, int out_size, void* d_ws, size_t ws_size,
                              hipStream_t stream) {
    const float* h   = (const float*)d_in[0];
    const int* src   = (const int*)d_in[1];
    const int* dst   = (const int*)d_in[2];
    const int* gid   = (const int*)d_in[3];
    const float* convw[4], *convb[4], *bng[4], *bnb[4];
    for (int i = 0; i < 4; i++) {
        convw[i] = (const float*)d_in[4 + 4 * i];
        convb[i] = (const float*)d_in[5 + 4 * i];
        bng[i]   = (const float*)d_in[6 + 4 * i];
        bnb[i]   = (const float*)d_in[7 + 4 * i];
    }
    const float* mw0 = (const float*)d_in[20];
    const float* mb0 = (const float*)d_in[21];
    const float* mw1 = (const float*)d_in[22];
    const float* mb1 = (const float*)d_in[23];
    const float* mw2 = (const float*)d_in[24];
    const float* mb2 = (const float*)d_in[25];

    const int N = in_sizes[0] / 32;
    const int E = in_sizes[1];
    const int G = out_size;
    const int nbuck = cdiv_h(N, BKN);          // <= MAXBUCK for N <= 131072
    const int chunk = cdiv_h(E, NSB);

    // workspace bump allocator (512B aligned)
    char* ws = (char*)d_ws;
    size_t off = 0;
    auto alloc = [&](size_t bytes) -> void* {
        void* p = ws + off;
        off += (bytes + 511) & ~(size_t)511;
        return p;
    };
    int* histT   = (int*)alloc((size_t)NSB * nbuck * 4);
    int* prefixB = (int*)alloc((size_t)nbuck * NSB * 4);
    int* totalP  = (int*)alloc((size_t)nbuck * 4);
    int* totalU  = (int*)alloc((size_t)nbuck * 4);
    int* basePp  = (int*)alloc((size_t)nbuck * 4);
    int* baseUp  = (int*)alloc((size_t)nbuck * 4);
    size_t ebufE = (size_t)E + (size_t)16 * NSB * nbuck;      // padded capacity (ints)
    size_t ovl   = ebufE * 4;
    size_t pB    = (size_t)N * 64;                            // p bf16: 64 B/node
    if (pB > ovl) ovl = pB;
    unsigned* ebuf = (unsigned*)alloc(ovl);                    // overlay: ebuf dead after k_sortb
    uint4* pb    = (uint4*)ebuf;
    int* col     = (int*)alloc((size_t)E * 4);
    int* rs      = (int*)alloc((size_t)N * 4);
    int* re      = (int*)alloc((size_t)N * 4);
    int* gstart  = (int*)alloc((size_t)(G + 1) * 4);
    uint4* y0b   = (uint4*)alloc((size_t)N * 64);              // bf16 y: 64 B/node
    uint4* y1b   = (uint4*)alloc((size_t)N * 64);
    uint4* y2b   = (uint4*)alloc((size_t)N * 64);
    float* y3    = (float*)alloc((size_t)N * 4);
    float* sSum  = (float*)alloc((size_t)4 * NSLOT * 32 * 4);
    float* sSq   = (float*)alloc((size_t)4 * NSLOT * 32 * 4);
    (void)ws_size; (void)n_in;

    const int NB_N = cdiv_h(N, 256);
    const int NB_AG = cdiv_h(N, 64);   // one node per 4-lane group
    const float invN = 1.f / (float)N;

    // edge grouping: two-pass deterministic scatter (zero global atomics) + per-bucket sort
    k_hist<<<NSB, 256, 0, stream>>>(dst, histT, sSum, sSq, E, nbuck, chunk);
    k_scanA<<<nbuck, 256, 0, stream>>>(histT, prefixB, totalP, totalU, gid, gstart, nbuck, N, G);
    k_scanB<<<1, 512, 0, stream>>>(totalP, totalU, basePp, baseUp, nbuck);
    k_scatter2<<<NSB, 256, 0, stream>>>(src, dst, basePp, prefixB, ebuf, E, nbuck, chunk);
    k_sortb<<<nbuck, 256, 0, stream>>>(ebuf, histT, basePp, prefixB, baseUp, col, rs, re, nbuck, N);

    // layer 0
    k_transform<0><<<NB_N, 256, 0, stream>>>(h, convw[0], nullptr, nullptr, nullptr, nullptr, pb, N, invN);
    k_aggregate<<<NB_AG, 256, 0, stream>>>(pb, rs, re, col, convb[0], y0b,
                                           sSum + 0 * NSLOT * 32, sSq + 0 * NSLOT * 32, N);
    // layer 1 (folds layer-0 BN finalize)
    k_transform<1><<<NB_N, 256, 0, stream>>>(y0b, convw[1], sSum + 0 * NSLOT * 32, sSq + 0 * NSLOT * 32,
                                             bng[0], bnb[0], pb, N, invN);
    k_aggregate<<<NB_AG, 256, 0, stream>>>(pb, rs, re, col, convb[1], y1b,
                                           sSum + 1 * NSLOT * 32, sSq + 1 * NSLOT * 32, N);
    // layer 2 (folds layer-1 BN finalize)
    k_transform<1><<<NB_N, 256, 0, stream>>>(y1b, convw[2], sSum + 1 * NSLOT * 32, sSq + 1 * NSLOT * 32,
                                             bng[1], bnb[1], pb, N, invN);
    k_aggregate<<<NB_AG, 256, 0, stream>>>(pb, rs, re, col, convb[2], y2b,
                                           sSum + 2 * NSLOT * 32, sSq + 2 * NSLOT * 32, N);
    // layer 3 (32 -> 1, pre-multiplied; folds layer-2 BN finalize)
    k_transform3<<<NB_N, 256, 0, stream>>>(y2b, convw[3], sSum + 2 * NSLOT * 32, sSq + 2 * NSLOT * 32,
                                           bng[2], bnb[2], (float*)pb, N, invN);
    k_aggregate3<<<NB_N, 256, 0, stream>>>((float*)pb, rs, re, col, convb[3], y3,
                                           sSum + 3 * NSLOT * 32, sSq + 3 * NSLOT * 32, N);

    // pooling + MLP (folds all BN coefs)
    k_pool_mlp<<<G, 256, 0, stream>>>(h, (const unsigned*)y0b, (const unsigned*)y1b, (const unsigned*)y2b,
                                      y3, sSum, sSq,
                                      bng[0], bnb[0], bng[1], bnb[1], bng[2], bnb[2], bng[3], bnb[3],
                                      gstart, mw0, mb0, mw1, mb1, mw2, mb2, (float*)d_out, invN);
}

// Round 4
// 286.536 us; speedup vs baseline: 1.6401x; 1.0705x over previous
//
#include <hip/hip_runtime.h>

#define NSLOT 32
#define BN_EPS 1e-5f
#define NSB 256             // scatter blocks (1 edge-slice each)
#define BKBITS 8
#define BKN 256             // nodes per bucket (= sort block size)
#define MAXBUCK 512         // LDS bound: nbuck = cdiv(N,256) <= 512 for N <= 131072

static inline int cdiv_h(int a, int b) { return (a + b - 1) / b; }

__device__ __forceinline__ float4 f4add(float4 a, float4 b) {
    return make_float4(a.x + b.x, a.y + b.y, a.z + b.z, a.w + b.w);
}

// bf16 round-to-nearest-even pack / unpack
__device__ __forceinline__ unsigned bf16rtn(float x) {
    unsigned u = __float_as_uint(x);
    return (u + 0x7FFFu + ((u >> 16) & 1u)) >> 16;
}
__device__ __forceinline__ unsigned bf16pack2(float lo, float hi) {
    return bf16rtn(lo) | (bf16rtn(hi) << 16);
}
__device__ __forceinline__ float bfLO(unsigned u) { return __uint_as_float(u << 16); }
__device__ __forceinline__ float bfHI(unsigned u) { return __uint_as_float(u & 0xFFFF0000u); }

// block-wide exclusive scan, 256 threads (4 waves)
__device__ __forceinline__ int blk_excl_scan256(int v, int t) {
    __shared__ int wsum[4];
    int l = t & 63, w = t >> 6;
    int incl = v;
#pragma unroll
    for (int off = 1; off < 64; off <<= 1) {
        int o = __shfl_up(incl, off, 64);
        if (l >= off) incl += o;
    }
    if (l == 63) wsum[w] = incl;
    __syncthreads();
    int wofs = 0;
#pragma unroll
    for (int i = 0; i < 4; i++) wofs += (i < w) ? wsum[i] : 0;
    __syncthreads();
    return wofs + incl - v;
}

// per-block BN coef compute from 32-slot partials (ch in [0,32))
__device__ __forceinline__ void bn_coef(const float* __restrict__ sSum, const float* __restrict__ sSq,
                                        const float* __restrict__ bg, const float* __restrict__ bb,
                                        float invN, int ch, float* aOut, float* cOut) {
    float S = 0.f, Q = 0.f;
#pragma unroll
    for (int s = 0; s < NSLOT; s++) { S += sSum[s * 32 + ch]; Q += sSq[s * 32 + ch]; }
    float m = S * invN;
    float var = Q * invN - m * m;
    if (var < 0.f) var = 0.f;
    float iv = rsqrtf(var + BN_EPS);
    float a = bg[ch] * iv;
    *aOut = a;
    *cOut = bb[ch] - m * a;
}

// ---------------- pass 1: [blocks < NSB] per-slice bucket histogram (+stats zero)
//                  [blocks >= NSB] packed transform0: pb = h @ W0 (independent of grouping) -----

__global__ __launch_bounds__(256) void k_hist_t0(const int* __restrict__ dst, int* __restrict__ histT,
                                                 float* __restrict__ sSum, float* __restrict__ sSq,
                                                 int E, int nbuck, int chunk,
                                                 const float* __restrict__ h, const float* __restrict__ W0,
                                                 uint4* __restrict__ pb, int N) {
    __shared__ int bins[MAXBUCK];
    __shared__ float sW[32][32];
    int t = threadIdx.x;
    if (blockIdx.x < NSB) {
        int k = blockIdx.x;
        if (k == 0) {    // zero BN stat slots (replaces memsets)
            for (int i = t; i < 4 * NSLOT * 32; i += 256) { sSum[i] = 0.f; sSq[i] = 0.f; }
        }
        for (int b = t; b < nbuck; b += 256) bins[b] = 0;
        __syncthreads();
        int lo = k * chunk, hi = lo + chunk; if (hi > E) hi = E;
        for (int i = lo + t; i < hi; i += 256) atomicAdd(&bins[dst[i] >> BKBITS], 1);
        __syncthreads();
        for (int b = t; b < nbuck; b += 256) histT[k * nbuck + b] = bins[b];
    } else {
        // transform0: one node per thread
        for (int i = t; i < 1024; i += 256) sW[i >> 5][i & 31] = W0[i];
        __syncthreads();
        int node = (blockIdx.x - NSB) * 256 + t;
        if (node >= N) return;
        float x[32];
        const float4* s4 = (const float4*)h + (size_t)node * 8;
#pragma unroll
        for (int q = 0; q < 8; q++) {
            float4 v = s4[q];
            x[4*q] = v.x; x[4*q+1] = v.y; x[4*q+2] = v.z; x[4*q+3] = v.w;
        }
        float acc[32];
#pragma unroll
        for (int f = 0; f < 32; f++) acc[f] = 0.f;
#pragma unroll
        for (int k = 0; k < 32; k++) {
            float xv = x[k];
#pragma unroll
            for (int f = 0; f < 32; f++) acc[f] += xv * sW[k][f];
        }
        uint4* d4 = pb + (size_t)node * 4;
#pragma unroll
        for (int q = 0; q < 4; q++) {
            uint4 o;
            o.x = bf16pack2(acc[8*q+0], acc[8*q+1]);
            o.y = bf16pack2(acc[8*q+2], acc[8*q+3]);
            o.z = bf16pack2(acc[8*q+4], acc[8*q+5]);
            o.w = bf16pack2(acc[8*q+6], acc[8*q+7]);
            d4[q] = o;
        }
    }
}

// ---------------- pass 1b: per-bucket scan over cells (+ folded gstart) ----------------

__global__ __launch_bounds__(256) void k_scanA(const int* __restrict__ histT, int* __restrict__ prefixB,
                                               int* __restrict__ totalP, int* __restrict__ totalU,
                                               const int* __restrict__ gid, int* __restrict__ gstart,
                                               int nbuck, int N, int G) {
    int b = blockIdx.x, k = threadIdx.x;
    int i = b * 256 + k;
    if (i < N) {
        int g = gid[i];
        int gp = (i == 0) ? -1 : gid[i - 1];
        for (int x = gp + 1; x <= g; ++x) gstart[x] = i;
        if (i == N - 1) { for (int x = g + 1; x <= G; ++x) gstart[x] = N; }
    }
    int c = histT[k * nbuck + b];
    int pad = (c + 15) & ~15;
    int ep = blk_excl_scan256(pad, k);
    prefixB[b * NSB + k] = ep;
    int ec = blk_excl_scan256(c, k);
    if (k == NSB - 1) { totalP[b] = ep + pad; totalU[b] = ec + c; }
}

// inline cross-bucket exclusive scan of a <=512-entry array into LDS (replaces the k_scanB kernel)
__device__ __forceinline__ void inline_scan512(const int* __restrict__ tot, int* __restrict__ sOut,
                                               int* __restrict__ sTot, int nbuck, int t) {
    int v0 = (t < nbuck) ? tot[t] : 0;
    int v1 = (256 + t < nbuck) ? tot[256 + t] : 0;
    int e0 = blk_excl_scan256(v0, t);
    if (t == 255) *sTot = e0 + v0;
    __syncthreads();
    int e1 = blk_excl_scan256(v1, t) + *sTot;
    sOut[t] = e0;
    sOut[256 + t] = e1;
    __syncthreads();
}

// ---------------- pass 2: deterministic scatter (LDS cursors, no global atomics) ----------------
// packed entry: (dst&255)<<24 | src   (requires N < 2^24)

__global__ __launch_bounds__(256) void k_scatter2(const int* __restrict__ src, const int* __restrict__ dst,
                                                  const int* __restrict__ totalP, const int* __restrict__ prefixB,
                                                  unsigned* __restrict__ ebuf, int E, int nbuck, int chunk) {
    __shared__ int cur[MAXBUCK];
    __shared__ int sBP[512];
    __shared__ int sTot;
    int k = blockIdx.x, t = threadIdx.x;
    inline_scan512(totalP, sBP, &sTot, nbuck, t);
    for (int b = t; b < nbuck; b += 256) cur[b] = sBP[b] + prefixB[b * NSB + k];
    __syncthreads();
    int lo = k * chunk, hi = lo + chunk; if (hi > E) hi = E;
    for (int i = lo + t; i < hi; i += 256) {
        int d = dst[i], s = src[i];
        int b = d >> BKBITS;
        int pos = atomicAdd(&cur[b], 1);
        ebuf[pos] = ((unsigned)(d & (BKN - 1)) << 24) | (unsigned)s;
    }
}

// ---------------- pass 3: per-bucket counting sort -> node-grouped compact col + rs/re ----------

__global__ __launch_bounds__(256) void k_sortb(const unsigned* __restrict__ ebuf, const int* __restrict__ histT,
                                               const int* __restrict__ totalP, const int* __restrict__ totalU,
                                               const int* __restrict__ prefixB,
                                               int* __restrict__ col, int* __restrict__ rs, int* __restrict__ re,
                                               int nbuck, int N) {
    __shared__ int binCnt[BKN], binStart[BKN], cursor[BKN];
    __shared__ int cellBase[NSB], cellCnt[NSB];
    __shared__ int sBP[512];
    __shared__ int sTotS;
    int b = blockIdx.x, t = threadIdx.x;
    inline_scan512(totalP, sBP, &sTotS, nbuck, t);
    int basePb = sBP[b];
    __syncthreads();
    inline_scan512(totalU, sBP, &sTotS, nbuck, t);
    int baseUb = sBP[b];
    cellBase[t] = basePb + prefixB[b * NSB + t];
    cellCnt[t]  = histT[t * nbuck + b];
    binCnt[t] = 0; cursor[t] = 0;
    __syncthreads();
    {
        int cb = cellBase[t], cc = cellCnt[t];
        for (int j = 0; j < cc; j++) atomicAdd(&binCnt[ebuf[cb + j] >> 24], 1);
    }
    __syncthreads();
    int bs = blk_excl_scan256(binCnt[t], t);
    binStart[t] = bs;
    __syncthreads();
    {
        int cb = cellBase[t], cc = cellCnt[t];
        for (int j = 0; j < cc; j++) {
            unsigned e = ebuf[cb + j];
            int l = e >> 24;
            int pos = binStart[l] + atomicAdd(&cursor[l], 1);
            col[baseUb + pos] = (int)(e & 0xFFFFFFu);
        }
    }
    int node = b * BKN + t;
    if (node < N) {
        rs[node] = baseUb + binStart[t];
        re[node] = baseUb + binStart[t] + binCnt[t];
    }
}

// ---------------- layer-0 aggregation: y0[v] = mean_{u->v} p[u] + b0; fused BN stats -----------
// bf16 p: 4 lanes/node, 16B (8 bf16 ch)/lane, one node per 4-lane group, pipelined 4-deep.

__global__ __launch_bounds__(256, 6) void k_aggregate(const uint4* __restrict__ pb, const int* __restrict__ rs,
                                                      const int* __restrict__ re, const int* __restrict__ col,
                                                      const float* __restrict__ bias,
                                                      uint4* __restrict__ yb, float* __restrict__ sSum,
                                                      float* __restrict__ sSq, int n) {
    __shared__ int scol[2048];
    __shared__ float sWS[4][32];
    __shared__ float sWQ[4][32];
    int t = threadIdx.x;
    int lane = t & 3;          // 16B chunk: channels lane*8 .. lane*8+7
    int grp = t >> 2;          // 0..63 : node within block
    int node0 = blockIdx.x * 64;
    int node = node0 + grp;
    int base0 = 0, len = 0;
    if (node0 < n) {
        int last = node0 + 63; if (last > n - 1) last = n - 1;
        base0 = rs[node0];
        len = re[last] - base0;
    }
    bool lds = (len > 0 && len <= 2048);
    if (lds) { for (int i = t; i < len; i += 256) scol[i] = col[base0 + i]; }
    __syncthreads();

    float accA[8], accB[8];
#pragma unroll
    for (int q = 0; q < 8; q++) { accA[q] = 0.f; accB[q] = 0.f; }
    float vout[8];
#pragma unroll
    for (int q = 0; q < 8; q++) vout[q] = 0.f;
    if (node < n) {
        int s0 = rs[node], s1 = re[node];
#define GATH2(vv, c) vv = pb[(size_t)(c) * 4 + lane]
#define ACC(dst, vv) \
        dst[0] += bfLO((vv).x); dst[1] += bfHI((vv).x); \
        dst[2] += bfLO((vv).y); dst[3] += bfHI((vv).y); \
        dst[4] += bfLO((vv).z); dst[5] += bfHI((vv).z); \
        dst[6] += bfLO((vv).w); dst[7] += bfHI((vv).w)
        if (lds) {
            int j = s0 - base0, j1 = s1 - base0;
            if (j + 4 <= j1) {
                uint4 g0, g1, g2, g3;
                GATH2(g0, scol[j]); GATH2(g1, scol[j + 1]); GATH2(g2, scol[j + 2]); GATH2(g3, scol[j + 3]);
                j += 4;
                for (; j + 4 <= j1; j += 4) {
                    uint4 h0, h1, h2, h3;
                    GATH2(h0, scol[j]); GATH2(h1, scol[j + 1]); GATH2(h2, scol[j + 2]); GATH2(h3, scol[j + 3]);
                    ACC(accA, g0); ACC(accB, g1); ACC(accA, g2); ACC(accB, g3);
                    g0 = h0; g1 = h1; g2 = h2; g3 = h3;
                }
                ACC(accA, g0); ACC(accB, g1); ACC(accA, g2); ACC(accB, g3);
            }
            for (; j < j1; ++j) { uint4 g; GATH2(g, scol[j]); ACC(accA, g); }
        } else {
            int j = s0;
            if (j + 4 <= s1) {
                uint4 g0, g1, g2, g3;
                GATH2(g0, col[j]); GATH2(g1, col[j + 1]); GATH2(g2, col[j + 2]); GATH2(g3, col[j + 3]);
                j += 4;
                for (; j + 4 <= s1; j += 4) {
                    uint4 h0, h1, h2, h3;
                    GATH2(h0, col[j]); GATH2(h1, col[j + 1]); GATH2(h2, col[j + 2]); GATH2(h3, col[j + 3]);
                    ACC(accA, g0); ACC(accB, g1); ACC(accA, g2); ACC(accB, g3);
                    g0 = h0; g1 = h1; g2 = h2; g3 = h3;
                }
                ACC(accA, g0); ACC(accB, g1); ACC(accA, g2); ACC(accB, g3);
            }
            for (; j < s1; ++j) { uint4 g; GATH2(g, col[j]); ACC(accA, g); }
        }
#undef GATH2
#undef ACC
        int deg = s1 - s0;
        float inv = (deg > 0) ? 1.f / (float)deg : 1.f;
        const float4* b4 = (const float4*)bias;
        float4 b0 = b4[lane * 2], b1 = b4[lane * 2 + 1];
        vout[0] = (accA[0] + accB[0]) * inv + b0.x;
        vout[1] = (accA[1] + accB[1]) * inv + b0.y;
        vout[2] = (accA[2] + accB[2]) * inv + b0.z;
        vout[3] = (accA[3] + accB[3]) * inv + b0.w;
        vout[4] = (accA[4] + accB[4]) * inv + b1.x;
        vout[5] = (accA[5] + accB[5]) * inv + b1.y;
        vout[6] = (accA[6] + accB[6]) * inv + b1.z;
        vout[7] = (accA[7] + accB[7]) * inv + b1.w;
        uint4 o;
        o.x = bf16pack2(vout[0], vout[1]);
        o.y = bf16pack2(vout[2], vout[3]);
        o.z = bf16pack2(vout[4], vout[5]);
        o.w = bf16pack2(vout[6], vout[7]);
        yb[(size_t)node * 4 + lane] = o;
    }
    // BN stats: wave shfl_xor reduce across the 16 groups, then cross-wave LDS combine
    float sqv[8];
#pragma unroll
    for (int q = 0; q < 8; q++) sqv[q] = vout[q] * vout[q];
#pragma unroll
    for (int off = 4; off < 64; off <<= 1) {
#pragma unroll
        for (int q = 0; q < 8; q++) {
            vout[q] += __shfl_xor(vout[q], off, 64);
            sqv[q]  += __shfl_xor(sqv[q],  off, 64);
        }
    }
    int w = t >> 6, l = t & 63;
    if (l < 4) {
#pragma unroll
        for (int q = 0; q < 8; q++) { sWS[w][l * 8 + q] = vout[q]; sWQ[w][l * 8 + q] = sqv[q]; }
    }
    __syncthreads();
    if (t < 32) {
        float S = sWS[0][t] + sWS[1][t] + sWS[2][t] + sWS[3][t];
        float Q = sWQ[0][t] + sWQ[1][t] + sWQ[2][t] + sWQ[3][t];
        int slot = blockIdx.x & (NSLOT - 1);
        atomicAdd(&sSum[slot * 32 + t], S);
        atomicAdd(&sSq[slot * 32 + t], Q);
    }
}

// ---------------- fused layers 1/2: y[v] = (mean_u relu(a*y_in[u]+c)) @ W + bias; BN stats -----
// mean-linearity: matmul commutes with the mean, so the former k_transform disappears.

__global__ __launch_bounds__(256, 4) void k_aggF(const uint4* __restrict__ yin, const int* __restrict__ rs,
                                                 const int* __restrict__ re, const int* __restrict__ col,
                                                 const float* __restrict__ W, const float* __restrict__ bias,
                                                 const float* __restrict__ pSum, const float* __restrict__ pSq,
                                                 const float* __restrict__ bg, const float* __restrict__ bb,
                                                 uint4* __restrict__ yout, float* __restrict__ sSum,
                                                 float* __restrict__ sSq, int n, float invN) {
    __shared__ int scol[2112];              // overlaid with sM[64][33] in the epilogue
    __shared__ float sW[32][32];
    __shared__ float sA[32], sC[32];
    __shared__ float sWS[4][32];
    __shared__ float sWQ[4][32];
    float* sM = (float*)scol;
    int t = threadIdx.x;
    for (int i = t; i < 1024; i += 256) sW[i >> 5][i & 31] = W[i];
    if (t < 32) bn_coef(pSum, pSq, bg, bb, invN, t, &sA[t], &sC[t]);
    int lane = t & 3, grp = t >> 2;
    int node0 = blockIdx.x * 64, node = node0 + grp;
    int base0 = 0, len = 0;
    if (node0 < n) {
        int last = node0 + 63; if (last > n - 1) last = n - 1;
        base0 = rs[node0];
        len = re[last] - base0;
    }
    bool lds = (len > 0 && len <= 2048);
    __syncthreads();                        // sA/sC ready
    if (lds) { for (int i = t; i < len; i += 256) scol[i] = col[base0 + i]; }
    __syncthreads();
    float a8[8], c8[8];
#pragma unroll
    for (int q = 0; q < 8; q++) { a8[q] = sA[lane * 8 + q]; c8[q] = sC[lane * 8 + q]; }

    float accA[8], accB[8];
#pragma unroll
    for (int q = 0; q < 8; q++) { accA[q] = 0.f; accB[q] = 0.f; }
    int s0 = 0, s1 = 0;
    if (node < n) {
        s0 = rs[node]; s1 = re[node];
#define GATH2(vv, c) vv = yin[(size_t)(c) * 4 + lane]
#define ACCF(dst, vv) do { \
        float x0 = bfLO((vv).x), x1 = bfHI((vv).x), x2 = bfLO((vv).y), x3 = bfHI((vv).y); \
        float x4 = bfLO((vv).z), x5 = bfHI((vv).z), x6 = bfLO((vv).w), x7 = bfHI((vv).w); \
        float r0 = fmaf(a8[0], x0, c8[0]); dst[0] += r0 > 0.f ? r0 : 0.f; \
        float r1 = fmaf(a8[1], x1, c8[1]); dst[1] += r1 > 0.f ? r1 : 0.f; \
        float r2 = fmaf(a8[2], x2, c8[2]); dst[2] += r2 > 0.f ? r2 : 0.f; \
        float r3 = fmaf(a8[3], x3, c8[3]); dst[3] += r3 > 0.f ? r3 : 0.f; \
        float r4 = fmaf(a8[4], x4, c8[4]); dst[4] += r4 > 0.f ? r4 : 0.f; \
        float r5 = fmaf(a8[5], x5, c8[5]); dst[5] += r5 > 0.f ? r5 : 0.f; \
        float r6 = fmaf(a8[6], x6, c8[6]); dst[6] += r6 > 0.f ? r6 : 0.f; \
        float r7 = fmaf(a8[7], x7, c8[7]); dst[7] += r7 > 0.f ? r7 : 0.f; } while (0)
        if (lds) {
            int j = s0 - base0, j1 = s1 - base0;
            if (j + 4 <= j1) {
                uint4 g0, g1, g2, g3;
                GATH2(g0, scol[j]); GATH2(g1, scol[j + 1]); GATH2(g2, scol[j + 2]); GATH2(g3, scol[j + 3]);
                j += 4;
                for (; j + 4 <= j1; j += 4) {
                    uint4 h0, h1, h2, h3;
                    GATH2(h0, scol[j]); GATH2(h1, scol[j + 1]); GATH2(h2, scol[j + 2]); GATH2(h3, scol[j + 3]);
                    ACCF(accA, g0); ACCF(accB, g1); ACCF(accA, g2); ACCF(accB, g3);
                    g0 = h0; g1 = h1; g2 = h2; g3 = h3;
                }
                ACCF(accA, g0); ACCF(accB, g1); ACCF(accA, g2); ACCF(accB, g3);
            }
            for (; j < j1; ++j) { uint4 g; GATH2(g, scol[j]); ACCF(accA, g); }
        } else {
            int j = s0;
            if (j + 4 <= s1) {
                uint4 g0, g1, g2, g3;
                GATH2(g0, col[j]); GATH2(g1, col[j + 1]); GATH2(g2, col[j + 2]); GATH2(g3, col[j + 3]);
                j += 4;
                for (; j + 4 <= s1; j += 4) {
                    uint4 h0, h1, h2, h3;
                    GATH2(h0, col[j]); GATH2(h1, col[j + 1]); GATH2(h2, col[j + 2]); GATH2(h3, col[j + 3]);
                    ACCF(accA, g0); ACCF(accB, g1); ACCF(accA, g2); ACCF(accB, g3);
                    g0 = h0; g1 = h1; g2 = h2; g3 = h3;
                }
                ACCF(accA, g0); ACCF(accB, g1); ACCF(accA, g2); ACCF(accB, g3);
            }
            for (; j < s1; ++j) { uint4 g; GATH2(g, col[j]); ACCF(accA, g); }
        }
#undef GATH2
    }
    // mean -> LDS (overlay of scol; all gathers done)
    __syncthreads();
    if (node < n) {
        int deg = s1 - s0;
        float inv = (deg > 0) ? 1.f / (float)deg : 1.f;
#pragma unroll
        for (int q = 0; q < 8; q++) sM[grp * 33 + lane * 8 + q] = (accA[q] + accB[q]) * inv;
    }
    __syncthreads();
    // epilogue: out[o] = sum_k m[k] * W[k][o] + bias[o]  (o = lane*8..+7)
    float vout[8];
#pragma unroll
    for (int q = 0; q < 8; q++) vout[q] = 0.f;
    if (node < n) {
        const float4* b4 = (const float4*)bias;
        float4 b0 = b4[lane * 2], b1 = b4[lane * 2 + 1];
        float out[8] = { b0.x, b0.y, b0.z, b0.w, b1.x, b1.y, b1.z, b1.w };
#pragma unroll
        for (int k = 0; k < 32; k++) {
            float mk = sM[grp * 33 + k];
#pragma unroll
            for (int q = 0; q < 8; q++) out[q] += mk * sW[k][lane * 8 + q];
        }
#pragma unroll
        for (int q = 0; q < 8; q++) vout[q] = out[q];
        uint4 o;
        o.x = bf16pack2(vout[0], vout[1]);
        o.y = bf16pack2(vout[2], vout[3]);
        o.z = bf16pack2(vout[4], vout[5]);
        o.w = bf16pack2(vout[6], vout[7]);
        yout[(size_t)node * 4 + lane] = o;
    }
    // BN stats (same layout as k_aggregate)
    float sqv[8];
#pragma unroll
    for (int q = 0; q < 8; q++) sqv[q] = vout[q] * vout[q];
#pragma unroll
    for (int off = 4; off < 64; off <<= 1) {
#pragma unroll
        for (int q = 0; q < 8; q++) {
            vout[q] += __shfl_xor(vout[q], off, 64);
            sqv[q]  += __shfl_xor(sqv[q],  off, 64);
        }
    }
    int w = t >> 6, l = t & 63;
    if (l < 4) {
#pragma unroll
        for (int q = 0; q < 8; q++) { sWS[w][l * 8 + q] = vout[q]; sWQ[w][l * 8 + q] = sqv[q]; }
    }
    __syncthreads();
    if (t < 32) {
        float S = sWS[0][t] + sWS[1][t] + sWS[2][t] + sWS[3][t];
        float Q = sWQ[0][t] + sWQ[1][t] + sWQ[2][t] + sWQ[3][t];
        int slot = blockIdx.x & (NSLOT - 1);
        atomicAdd(&sSum[slot * 32 + t], S);
        atomicAdd(&sSq[slot * 32 + t], Q);
    }
}

// ---------------- fused layer 3: y3[v] = (mean_u relu(a*y2[u]+c)) . w3 + b3; BN stats ----------

__global__ __launch_bounds__(256, 4) void k_aggF3(const uint4* __restrict__ yin, const int* __restrict__ rs,
                                                  const int* __restrict__ re, const int* __restrict__ col,
                                                  const float* __restrict__ w3, const float* __restrict__ b3,
                                                  const float* __restrict__ pSum, const float* __restrict__ pSq,
                                                  const float* __restrict__ bg, const float* __restrict__ bb,
                                                  float* __restrict__ y3, float* __restrict__ sSum,
                                                  float* __restrict__ sSq, int n, float invN) {
    __shared__ int scol[2048];
    __shared__ float sA[32], sC[32], sw[32];
    __shared__ float sWS3[4], sWQ3[4];
    int t = threadIdx.x;
    if (t < 32) { sw[t] = w3[t]; bn_coef(pSum, pSq, bg, bb, invN, t, &sA[t], &sC[t]); }
    int lane = t & 3, grp = t >> 2;
    int node0 = blockIdx.x * 64, node = node0 + grp;
    int base0 = 0, len = 0;
    if (node0 < n) {
        int last = node0 + 63; if (last > n - 1) last = n - 1;
        base0 = rs[node0];
        len = re[last] - base0;
    }
    bool lds = (len > 0 && len <= 2048);
    __syncthreads();
    if (lds) { for (int i = t; i < len; i += 256) scol[i] = col[base0 + i]; }
    __syncthreads();
    float a8[8], c8[8], w8[8];
#pragma unroll
    for (int q = 0; q < 8; q++) { a8[q] = sA[lane*8+q]; c8[q] = sC[lane*8+q]; w8[q] = sw[lane*8+q]; }

    float accA[8], accB[8];
#pragma unroll
    for (int q = 0; q < 8; q++) { accA[q] = 0.f; accB[q] = 0.f; }
    float yv = 0.f;
    bool valid = (node < n);
    if (valid) {
        int s0 = rs[node], s1 = re[node];
#define GATH2(vv, c) vv = yin[(size_t)(c) * 4 + lane]
        if (lds) {
            int j = s0 - base0, j1 = s1 - base0;
            if (j + 4 <= j1) {
                uint4 g0, g1, g2, g3;
                GATH2(g0, scol[j]); GATH2(g1, scol[j + 1]); GATH2(g2, scol[j + 2]); GATH2(g3, scol[j + 3]);
                j += 4;
                for (; j + 4 <= j1; j += 4) {
                    uint4 h0, h1, h2, h3;
                    GATH2(h0, scol[j]); GATH2(h1, scol[j + 1]); GATH2(h2, scol[j + 2]); GATH2(h3, scol[j + 3]);
                    ACCF(accA, g0); ACCF(accB, g1); ACCF(accA, g2); ACCF(accB, g3);
                    g0 = h0; g1 = h1; g2 = h2; g3 = h3;
                }
                ACCF(accA, g0); ACCF(accB, g1); ACCF(accA, g2); ACCF(accB, g3);
            }
            for (; j < j1; ++j) { uint4 g; GATH2(g, scol[j]); ACCF(accA, g); }
        } else {
            int j = s0;
            if (j + 4 <= s1) {
                uint4 g0, g1, g2, g3;
                GATH2(g0, col[j]); GATH2(g1, col[j + 1]); GATH2(g2, col[j + 2]); GATH2(g3, col[j + 3]);
                j += 4;
                for (; j + 4 <= s1; j += 4) {
                    uint4 h0, h1, h2, h3;
                    GATH2(h0, col[j]); GATH2(h1, col[j + 1]); GATH2(h2, col[j + 2]); GATH2(h3, col[j + 3]);
                    ACCF(accA, g0); ACCF(accB, g1); ACCF(accA, g2); ACCF(accB, g3);
                    g0 = h0; g1 = h1; g2 = h2; g3 = h3;
                }
                ACCF(accA, g0); ACCF(accB, g1); ACCF(accA, g2); ACCF(accB, g3);
            }
            for (; j < s1; ++j) { uint4 g; GATH2(g, col[j]); ACCF(accA, g); }
        }
#undef GATH2
#undef ACCF
        int deg = s1 - s0;
        float inv = (deg > 0) ? 1.f / (float)deg : 1.f;
        float part = 0.f;
#pragma unroll
        for (int q = 0; q < 8; q++) part += (accA[q] + accB[q]) * w8[q];
        part *= inv;
        // reduce across the 4-lane group
        part += __shfl_xor(part, 1, 64);
        part += __shfl_xor(part, 2, 64);
        yv = part + b3[0];
        if (lane == 0) y3[node] = yv;
    }
    float sv = (valid && lane == 0) ? yv : 0.f;
    float sq = sv * sv;
#pragma unroll
    for (int off = 1; off < 64; off <<= 1) {
        sv += __shfl_xor(sv, off, 64);
        sq += __shfl_xor(sq, off, 64);
    }
    int w = t >> 6;
    if ((t & 63) == 0) { sWS3[w] = sv; sWQ3[w] = sq; }
    __syncthreads();
    if (t == 0) {
        float S = sWS3[0] + sWS3[1] + sWS3[2] + sWS3[3];
        float Q = sWQ3[0] + sWQ3[1] + sWQ3[2] + sWQ3[3];
        int slot = blockIdx.x & (NSLOT - 1);
        atomicAdd(&sSum[slot * 32], S);
        atomicAdd(&sSq[slot * 32], Q);
    }
}

// ---------------- per-graph mean pool + MLP (folds all 97 BN coefs; bf16 y inputs) --------------

__global__ __launch_bounds__(256) void k_pool_mlp(const float* __restrict__ h,
                                                  const unsigned* __restrict__ y0b,
                                                  const unsigned* __restrict__ y1b,
                                                  const unsigned* __restrict__ y2b,
                                                  const float* __restrict__ y3,
                                                  const float* __restrict__ sSum, const float* __restrict__ sSq,
                                                  const float* __restrict__ bg0, const float* __restrict__ bb0,
                                                  const float* __restrict__ bg1, const float* __restrict__ bb1,
                                                  const float* __restrict__ bg2, const float* __restrict__ bb2,
                                                  const float* __restrict__ bg3, const float* __restrict__ bb3,
                                                  const int* __restrict__ gstart,
                                                  const float* __restrict__ w0, const float* __restrict__ b0,
                                                  const float* __restrict__ w1, const float* __restrict__ b1,
                                                  const float* __restrict__ w2, const float* __restrict__ b2,
                                                  float* __restrict__ out, float invN) {
    __shared__ float pcA[128], pcC[128];
    int g = blockIdx.x;
    int t = threadIdx.x;
    if (t < 97) {
        int layer = (t == 96) ? 3 : (t >> 5);
        int ch = t & 31;
        const float* bg = (layer == 0) ? bg0 : (layer == 1) ? bg1 : (layer == 2) ? bg2 : bg3;
        const float* bb = (layer == 0) ? bb0 : (layer == 1) ? bb1 : (layer == 2) ? bb2 : bb3;
        bn_coef(sSum + layer * NSLOT * 32, sSq + layer * NSLOT * 32, bg, bb, invN, ch, &pcA[t], &pcC[t]);
    }
    __syncthreads();
    int s0 = gstart[g], s1 = gstart[g + 1];
    int lane = t & 31, slot = t >> 5;
    int arr = lane >> 3, sub = lane & 7;
    const unsigned* yb = (arr == 1) ? y0b : (arr == 2) ? y1b : y2b;
    float4 a4 = make_float4(1.f, 1.f, 1.f, 1.f);
    float4 c4 = make_float4(0.f, 0.f, 0.f, 0.f);
    bool aff = (arr > 0);
    if (aff) {
        a4 = ((const float4*)pcA)[(arr - 1) * 8 + sub];
        c4 = ((const float4*)pcC)[(arr - 1) * 8 + sub];
    }
    float4 acc = make_float4(0.f, 0.f, 0.f, 0.f);
    for (int n = s0 + slot; n < s1; n += 8) {
        float4 v;
        if (arr == 0) {
            v = ((const float4*)h)[(size_t)n * 8 + sub];
        } else {
            uint2 u = ((const uint2*)yb)[(size_t)n * 8 + sub];   // 4 bf16 ch
            v = make_float4(bfLO(u.x), bfHI(u.x), bfLO(u.y), bfHI(u.y));
        }
        if (aff) {
            float vx = fmaf(a4.x, v.x, c4.x); vx = vx > 0.f ? vx : 0.f;
            float vy = fmaf(a4.y, v.y, c4.y); vy = vy > 0.f ? vy : 0.f;
            float vz = fmaf(a4.z, v.z, c4.z); vz = vz > 0.f ? vz : 0.f;
            float vw = fmaf(a4.w, v.w, c4.w); vw = vw > 0.f ? vw : 0.f;
            v = make_float4(vx, vy, vz, vw);
        }
        acc = f4add(acc, v);
    }
    // y3 channel: all 256 threads accumulate, wave reduce, cross-wave combine in sY[4]
    float ys = 0.f;
    {
        float a = pcA[96], c = pcC[96];
        for (int n = s0 + t; n < s1; n += 256) {
            float v = fmaf(a, y3[n], c);
            ys += v > 0.f ? v : 0.f;
        }
    }
#pragma unroll
    for (int off = 1; off < 64; off <<= 1) ys += __shfl_xor(ys, off, 64);
    __shared__ float sP[8][128];
    __shared__ float sY[4];
    if ((t & 63) == 0) sY[t >> 6] = ys;
    ((float4*)&sP[slot][lane * 4])[0] = acc;
    __syncthreads();
    __shared__ float hg[129];
    __shared__ float hid1[128];
    __shared__ float hid2[64];
    float inv = (s1 > s0) ? 1.f / (float)(s1 - s0) : 1.f;
    if (t < 128) {
        float S = 0.f;
#pragma unroll
        for (int s = 0; s < 8; s++) S += sP[s][t];
        hg[t] = S * inv;
    } else if (t == 128) {
        float S = sY[0] + sY[1] + sY[2] + sY[3];
        hg[128] = S * inv;
    }
    __syncthreads();
    if (t < 128) {
        float a = b0[t];
        for (int i = 0; i < 129; i++) a += hg[i] * w0[i * 128 + t];
        hid1[t] = a > 0.f ? a : 0.f;
    }
    __syncthreads();
    if (t < 64) {
        float a = b1[t];
        for (int i = 0; i < 128; i++) a += hid1[i] * w1[i * 64 + t];
        hid2[t] = a > 0.f ? a : 0.f;
    }
    __syncthreads();
    if (t < 64) {
        float v = hid2[t] * w2[t];
        for (int off = 32; off > 0; off >>= 1) v += __shfl_down(v, off, 64);
        if (t == 0) out[g] = v + b2[0];
    }
}

// ---------------- launcher (9 dispatches) ----------------

extern "C" void kernel_launch(void* const* d_in, const int* in_sizes, int n_in,
                              void* d_out, int out_size, void* d_ws, size_t ws_size,
                              hipStream_t stream) {
    const float* h   = (const float*)d_in[0];
    const int* src   = (const int*)d_in[1];
    const int* dst   = (const int*)d_in[2];
    const int* gid   = (const int*)d_in[3];
    const float* convw[4], *convb[4], *bng[4], *bnb[4];
    for (int i = 0; i < 4; i++) {
        convw[i] = (const float*)d_in[4 + 4 * i];
        convb[i] = (const float*)d_in[5 + 4 * i];
        bng[i]   = (const float*)d_in[6 + 4 * i];
        bnb[i]   = (const float*)d_in[7 + 4 * i];
    }
    const float* mw0 = (const float*)d_in[20];
    const float* mb0 = (const float*)d_in[21];
    const float* mw1 = (const float*)d_in[22];
    const float* mb1 = (const float*)d_in[23];
    const float* mw2 = (const float*)d_in[24];
    const float* mb2 = (const float*)d_in[25];

    const int N = in_sizes[0] / 32;
    const int E = in_sizes[1];
    const int G = out_size;
    const int nbuck = cdiv_h(N, BKN);          // <= MAXBUCK for N <= 131072
    const int chunk = cdiv_h(E, NSB);

    // workspace bump allocator (512B aligned)
    char* ws = (char*)d_ws;
    size_t off = 0;
    auto alloc = [&](size_t bytes) -> void* {
        void* p = ws + off;
        off += (bytes + 511) & ~(size_t)511;
        return p;
    };
    int* histT   = (int*)alloc((size_t)NSB * nbuck * 4);
    int* prefixB = (int*)alloc((size_t)nbuck * NSB * 4);
    int* totalP  = (int*)alloc((size_t)nbuck * 4);
    int* totalU  = (int*)alloc((size_t)nbuck * 4);
    size_t ebufE = (size_t)E + (size_t)16 * NSB * nbuck;      // padded capacity (ints)
    unsigned* ebuf = (unsigned*)alloc(ebufE * 4);
    uint4* pb    = (uint4*)alloc((size_t)N * 64);              // p bf16: 64 B/node (concurrent w/ ebuf now)
    int* col     = (int*)alloc((size_t)E * 4);
    int* rs      = (int*)alloc((size_t)N * 4);
    int* re      = (int*)alloc((size_t)N * 4);
    int* gstart  = (int*)alloc((size_t)(G + 1) * 4);
    uint4* y0b   = (uint4*)alloc((size_t)N * 64);              // bf16 y: 64 B/node
    uint4* y1b   = (uint4*)alloc((size_t)N * 64);
    uint4* y2b   = (uint4*)alloc((size_t)N * 64);
    float* y3    = (float*)alloc((size_t)N * 4);
    float* sSum  = (float*)alloc((size_t)4 * NSLOT * 32 * 4);
    float* sSq   = (float*)alloc((size_t)4 * NSLOT * 32 * 4);
    (void)ws_size; (void)n_in;

    const int NB_N = cdiv_h(N, 256);
    const int NB_AG = cdiv_h(N, 64);   // one node per 4-lane group
    const float invN = 1.f / (float)N;

    // 1: histogram (blocks 0..NSB) + packed transform0 (blocks NSB..NSB+NB_N)
    k_hist_t0<<<NSB + NB_N, 256, 0, stream>>>(dst, histT, sSum, sSq, E, nbuck, chunk,
                                              h, convw[0], pb, N);
    // 2: per-bucket cell scan + gstart
    k_scanA<<<nbuck, 256, 0, stream>>>(histT, prefixB, totalP, totalU, gid, gstart, nbuck, N, G);
    // 3: deterministic scatter (inline cross-bucket scan)
    k_scatter2<<<NSB, 256, 0, stream>>>(src, dst, totalP, prefixB, ebuf, E, nbuck, chunk);
    // 4: per-bucket counting sort -> col/rs/re (inline cross-bucket scans)
    k_sortb<<<nbuck, 256, 0, stream>>>(ebuf, histT, totalP, totalU, prefixB, col, rs, re, nbuck, N);
    // 5: layer-0 aggregate (gathers pb)
    k_aggregate<<<NB_AG, 256, 0, stream>>>(pb, rs, re, col, convb[0], y0b,
                                           sSum + 0 * NSLOT * 32, sSq + 0 * NSLOT * 32, N);
    // 6: fused layer 1 (BN0 affine + relu on gather, mean, @W1)
    k_aggF<<<NB_AG, 256, 0, stream>>>(y0b, rs, re, col, convw[1], convb[1],
                                      sSum + 0 * NSLOT * 32, sSq + 0 * NSLOT * 32, bng[0], bnb[0],
                                      y1b, sSum + 1 * NSLOT * 32, sSq + 1 * NSLOT * 32, N, invN);
    // 7: fused layer 2
    k_aggF<<<NB_AG, 256, 0, stream>>>(y1b, rs, re, col, convw[2], convb[2],
                                      sSum + 1 * NSLOT * 32, sSq + 1 * NSLOT * 32, bng[1], bnb[1],
                                      y2b, sSum + 2 * NSLOT * 32, sSq + 2 * NSLOT * 32, N, invN);
    // 8: fused layer 3 (scalar output)
    k_aggF3<<<NB_AG, 256, 0, stream>>>(y2b, rs, re, col, convw[3], convb[3],
                                       sSum + 2 * NSLOT * 32, sSq + 2 * NSLOT * 32, bng[2], bnb[2],
                                       y3, sSum + 3 * NSLOT * 32, sSq + 3 * NSLOT * 32, N, invN);
    // 9: pooling + MLP
    k_pool_mlp<<<G, 256, 0, stream>>>(h, (const unsigned*)y0b, (const unsigned*)y1b, (const unsigned*)y2b,
                                      y3, sSum, sSq,
                                      bng[0], bnb[0], bng[1], bnb[1], bng[2], bnb[2], bng[3], bnb[3],
                                      gstart, mw0, mb0, mw1, mb1, mw2, mb2, (float*)d_out, invN);
}